// Round 2
// baseline (1017.488 us; speedup 1.0000x reference)
//
#include <hip/hip_runtime.h>
#include <math.h>

#define BATCH 4
#define HH 128
#define WWW 128
#define LLEN (HH*WWW)      // 16384
#define CIN 96
#define DI 192
#define KDIR 4
#define NCH 256            // number of chunks
#define PCH 64             // chunk length  (NCH*PCH == LLEN)

// ---------------- Kernel 1: in_proj (1x1 conv, 96 -> 192) ----------------
// x: (B, 96, L) channel-major.  t0: (B, L, 192) row-major rows.
__global__ __launch_bounds__(256) void k_inproj(const float* __restrict__ x,
                                                const float* __restrict__ w,
                                                float* __restrict__ t0) {
    __shared__ float xin[CIN * 64];     // [c][l] stride 64
    __shared__ float wt[CIN * 65];      // [c][o] stride 65 (pad)
    int bid = blockIdx.x;
    int b = bid >> 8;                   // 256 l-tiles per batch
    int l0 = (bid & 255) << 6;
    int t = threadIdx.x;
    for (int i = 0; i < 24; ++i) {
        int idx = t + i * 256;          // 0..6143
        int c = idx >> 6, l = idx & 63;
        xin[c * 64 + l] = x[((size_t)(b * CIN + c)) * LLEN + l0 + l];
    }
    int o_lane = t & 63;
    int lgrp = t >> 6;                  // 0..3
    for (int ot = 0; ot < 3; ++ot) {
        __syncthreads();
        for (int i = 0; i < 24; ++i) {
            int idx = t + i * 256;      // 0..6143 over (o,c), c fastest
            int o = idx / 96, c = idx - o * 96;
            wt[c * 65 + o] = w[(ot * 64 + o) * 96 + c];
        }
        __syncthreads();
        float acc[16];
        #pragma unroll
        for (int i = 0; i < 16; ++i) acc[i] = 0.f;
        int lb = lgrp * 16;
        for (int c = 0; c < CIN; ++c) {
            float wv = wt[c * 65 + o_lane];
            #pragma unroll
            for (int i = 0; i < 16; ++i) acc[i] += wv * xin[c * 64 + lb + i];
        }
        int o = ot * 64 + o_lane;
        for (int i = 0; i < 16; ++i)
            t0[((size_t)(b * LLEN) + l0 + lb + i) * DI + o] = acc[i];
    }
}

// ------------- Kernel 2: depthwise 3x3 conv + bias + SiLU ---------------
// t0: (B, L, 192) -> xf: (B, L, 192)
__global__ __launch_bounds__(192) void k_dwconv(const float* __restrict__ t0,
                                                const float* __restrict__ cw,
                                                const float* __restrict__ cb,
                                                float* __restrict__ xf) {
    int l = blockIdx.x & (LLEN - 1);
    int b = blockIdx.x >> 14;
    int d = threadIdx.x;
    int h = l >> 7, w = l & 127;
    float acc = cb[d];
    #pragma unroll
    for (int kh = 0; kh < 3; ++kh) {
        int hh = h + kh - 1;
        if (hh < 0 || hh >= HH) continue;
        #pragma unroll
        for (int kw = 0; kw < 3; ++kw) {
            int ww2 = w + kw - 1;
            if (ww2 < 0 || ww2 >= WWW) continue;
            acc += cw[d * 9 + kh * 3 + kw] *
                   t0[((size_t)(b * LLEN) + hh * WWW + ww2) * DI + d];
        }
    }
    float s = acc / (1.f + expf(-acc));   // SiLU
    xf[((size_t)(b * LLEN) + l) * DI + d] = s;
}

// ------- Kernels 3/5: fused gather + x_proj + dt_proj + scan ------------
// PHASE 1: emit per-chunk affine summary (Aprod, Bsum).
// PHASE 3: replay with carried-in h, emit ys, atomic-scatter into y.
template <int PHASE>
__global__ __launch_bounds__(256) void k_scan(const float* __restrict__ xf,
                                              const int* __restrict__ sids,
                                              const float* __restrict__ xpw,
                                              const float* __restrict__ dtw,
                                              const float* __restrict__ dtb,
                                              const float* __restrict__ alog,
                                              const float* __restrict__ dsv,
                                              float* __restrict__ cA,
                                              float* __restrict__ cB,
                                              const float* __restrict__ hin,
                                              float* __restrict__ y) {
    __shared__ int sid[PCH];
    __shared__ float xs[PCH * 193];     // [p][d] stride 193 (pad)
    __shared__ float xdbl[PCH * 8];     // [p][c] 8 proj channels
    int bid = blockIdx.x;
    int c = bid & (NCH - 1);
    int k = (bid >> 8) & 3;
    int b = bid >> 10;
    int t = threadIdx.x;
    if (t < PCH) sid[t] = sids[k * LLEN + c * PCH + t];
    __syncthreads();
    for (int i = 0; i < 48; ++i) {
        int idx = t + i * 256;          // 0..12287
        int p = idx / DI;
        int d = idx - p * DI;
        xs[p * 193 + d] = xf[((size_t)(b * LLEN) + sid[p]) * DI + d];
    }
    __syncthreads();
    // x_dbl: 512 dot products of length 192 (8 channels x 64 positions)
    #pragma unroll
    for (int jj = 2 * t; jj <= 2 * t + 1; ++jj) {
        int co = jj >> 6;
        int p = jj & 63;
        const float* wrow = xpw + (k * 8 + co) * DI;
        float acc = 0.f;
        for (int d = 0; d < DI; ++d) acc += wrow[d] * xs[p * 193 + d];
        xdbl[p * 8 + co] = acc;
    }
    __syncthreads();
    if (t < DI) {
        int d = t;
        float wr[6];
        #pragma unroll
        for (int r = 0; r < 6; ++r) wr[r] = dtw[(k * DI + d) * 6 + r];
        float bias = dtb[k * DI + d];
        float A = -expf(alog[k * DI + d]);
        float Dv = dsv[k * DI + d];
        size_t cidx = ((size_t)((b * KDIR + k) * NCH + c)) * DI + d;
        float Ar = 1.f, Br = 0.f, h = 0.f;
        if (PHASE == 3) h = hin[cidx];
        for (int p = 0; p < PCH; ++p) {
            float s = bias;
            #pragma unroll
            for (int r = 0; r < 6; ++r) s += wr[r] * xdbl[p * 8 + r];
            float delta = (s > 20.f) ? s : log1pf(expf(s));
            float a = expf(delta * A);
            float u = xs[p * 193 + d];
            float bu = delta * xdbl[p * 8 + 6] * u;
            if (PHASE == 1) {
                Ar *= a;
                Br = a * Br + bu;
            } else {
                h = a * h + bu;
                float ys = xdbl[p * 8 + 7] * h + Dv * u;
                atomicAdd(&y[((size_t)(b * LLEN) + sid[p]) * DI + d], ys);
            }
        }
        if (PHASE == 1) { cA[cidx] = Ar; cB[cidx] = Br; }
    }
}

// ------------- Kernel 4: scan of chunk summaries (tiny) -----------------
__global__ __launch_bounds__(192) void k_chunkscan(const float* __restrict__ cA,
                                                   const float* __restrict__ cB,
                                                   float* __restrict__ hin) {
    int bk = blockIdx.x;    // 0..15 = (b,k)
    int d = threadIdx.x;
    float h = 0.f;
    for (int cc = 0; cc < NCH; ++cc) {
        size_t idx = ((size_t)(bk * NCH + cc)) * DI + d;
        hin[idx] = h;
        h = cA[idx] * h + cB[idx];
    }
}

// ------------- Kernel 6: GELU + out_proj (192 -> 96) --------------------
// y: (B, L, 192) -> out: (B, 96, L)
__global__ __launch_bounds__(256) void k_out(const float* __restrict__ y,
                                             const float* __restrict__ wo,
                                             float* __restrict__ out) {
    __shared__ float gy[DI * 65];       // [c][l] stride 65 (pad)
    int bid = blockIdx.x;
    int b = bid >> 8;
    int l0 = (bid & 255) << 6;
    int t = threadIdx.x;
    for (int i = 0; i < 48; ++i) {
        int idx = t + i * 256;          // 0..12287
        int l = idx / DI;
        int cc = idx - l * DI;
        float v = y[((size_t)(b * LLEN) + l0 + l) * DI + cc];
        float g = 0.5f * v * (1.f + tanhf(0.7978845608028654f * (v + 0.044715f * v * v * v)));
        gy[cc * 65 + l] = g;
    }
    __syncthreads();
    int l = t & 63;
    int og = t >> 6;                    // 0..3, 24 output channels each
    float acc[24];
    #pragma unroll
    for (int i = 0; i < 24; ++i) acc[i] = 0.f;
    int ob = og * 24;
    for (int cc = 0; cc < DI; ++cc) {
        float gv = gy[cc * 65 + l];
        #pragma unroll
        for (int i = 0; i < 24; ++i) acc[i] += wo[(ob + i) * DI + cc] * gv;
    }
    for (int i = 0; i < 24; ++i)
        out[((size_t)(b * CIN) + ob + i) * LLEN + l0 + l] = acc[i];
}

extern "C" void kernel_launch(void* const* d_in, const int* in_sizes, int n_in,
                              void* d_out, int out_size, void* d_ws, size_t ws_size,
                              hipStream_t stream) {
    const float* x        = (const float*)d_in[0];
    const int*   scan_ids = (const int*)d_in[1];
    // d_in[2] inverse_ids: unused (scatter with scan_ids instead)
    const float* in_proj_w = (const float*)d_in[3];
    const float* conv_w    = (const float*)d_in[4];
    const float* conv_b    = (const float*)d_in[5];
    const float* xpw       = (const float*)d_in[6];
    const float* dtw       = (const float*)d_in[7];
    const float* dtb       = (const float*)d_in[8];
    const float* alog      = (const float*)d_in[9];
    const float* dsv       = (const float*)d_in[10];
    const float* wo        = (const float*)d_in[11];
    float* out = (float*)d_out;

    float* ws = (float*)d_ws;
    const size_t NBL = (size_t)BATCH * LLEN * DI;       // 12.58M floats
    const size_t NCK = (size_t)BATCH * KDIR * NCH * DI; // 786432 floats
    float* t0  = ws;            // in_proj output; later reused as y
    float* xf  = t0 + NBL;      // post-conv SiLU activations (B,L,D)
    float* cA  = xf + NBL;
    float* cB  = cA + NCK;
    float* hin = cB + NCK;
    float* y   = t0;            // reuse t0 (dead after k_dwconv)

    k_inproj<<<BATCH * 256, 256, 0, stream>>>(x, in_proj_w, t0);
    k_dwconv<<<BATCH * LLEN, 192, 0, stream>>>(t0, conv_w, conv_b, xf);
    hipMemsetAsync(y, 0, NBL * sizeof(float), stream);
    k_scan<1><<<BATCH * KDIR * NCH, 256, 0, stream>>>(xf, scan_ids, xpw, dtw, dtb,
                                                      alog, dsv, cA, cB, nullptr, nullptr);
    k_chunkscan<<<BATCH * KDIR, 192, 0, stream>>>(cA, cB, hin);
    k_scan<3><<<BATCH * KDIR * NCH, 256, 0, stream>>>(xf, scan_ids, xpw, dtw, dtb,
                                                      alog, dsv, cA, cB, hin, y);
    k_out<<<BATCH * 256, 256, 0, stream>>>(y, wo, out);
}

// Round 3
// 720.542 us; speedup vs baseline: 1.4121x; 1.4121x over previous
//
#include <hip/hip_runtime.h>
#include <math.h>

#define BATCH 4
#define HH 128
#define WWW 128
#define LLEN (HH*WWW)      // 16384
#define CIN 96
#define DI 192
#define KDIR 4
#define NCH 256            // number of chunks
#define PCH 64             // chunk length  (NCH*PCH == LLEN)

// ---------------- Kernel 1: in_proj (1x1 conv, 96 -> 192) ----------------
// x: (B, 96, L) channel-major.  t0: (B, L, 192) row-major rows.
__global__ __launch_bounds__(256) void k_inproj(const float* __restrict__ x,
                                                const float* __restrict__ w,
                                                float* __restrict__ t0) {
    __shared__ float xin[CIN * 64];     // [c][l] stride 64
    __shared__ float wt[CIN * 65];      // [c][o] stride 65 (pad)
    int bid = blockIdx.x;
    int b = bid >> 8;                   // 256 l-tiles per batch
    int l0 = (bid & 255) << 6;
    int t = threadIdx.x;
    for (int i = 0; i < 24; ++i) {
        int idx = t + i * 256;          // 0..6143
        int c = idx >> 6, l = idx & 63;
        xin[c * 64 + l] = x[((size_t)(b * CIN + c)) * LLEN + l0 + l];
    }
    int o_lane = t & 63;
    int lgrp = t >> 6;                  // 0..3
    for (int ot = 0; ot < 3; ++ot) {
        __syncthreads();
        for (int i = 0; i < 24; ++i) {
            int idx = t + i * 256;      // 0..6143 over (o,c), c fastest
            int o = idx / 96, c = idx - o * 96;
            wt[c * 65 + o] = w[(ot * 64 + o) * 96 + c];
        }
        __syncthreads();
        float acc[16];
        #pragma unroll
        for (int i = 0; i < 16; ++i) acc[i] = 0.f;
        int lb = lgrp * 16;
        for (int c = 0; c < CIN; ++c) {
            float wv = wt[c * 65 + o_lane];
            #pragma unroll
            for (int i = 0; i < 16; ++i) acc[i] += wv * xin[c * 64 + lb + i];
        }
        int o = ot * 64 + o_lane;
        for (int i = 0; i < 16; ++i)
            t0[((size_t)(b * LLEN) + l0 + lb + i) * DI + o] = acc[i];
    }
}

// ------------- Kernel 2: depthwise 3x3 conv + bias + SiLU ---------------
// t0: (B, L, 192) -> xf: (B, L, 192).  8 outputs (along w) per thread.
__global__ __launch_bounds__(192) void k_dwconv(const float* __restrict__ t0,
                                                const float* __restrict__ cw,
                                                const float* __restrict__ cb,
                                                float* __restrict__ xf) {
    int bid = blockIdx.x;
    int wt = (bid & 15) << 3;           // 16 tiles of 8 along w
    int h  = (bid >> 4) & (HH - 1);
    int b  = bid >> 11;
    int d  = threadIdx.x;
    float acc[8];
    float bias = cb[d];
    #pragma unroll
    for (int j = 0; j < 8; ++j) acc[j] = bias;
    #pragma unroll
    for (int kh = 0; kh < 3; ++kh) {
        int hh = h + kh - 1;
        if (hh < 0 || hh >= HH) continue;
        float w0v = cw[d * 9 + kh * 3 + 0];
        float w1v = cw[d * 9 + kh * 3 + 1];
        float w2v = cw[d * 9 + kh * 3 + 2];
        const float* rowp = t0 + ((size_t)(b * LLEN) + hh * WWW) * DI + d;
        float v[10];
        #pragma unroll
        for (int j = 0; j < 10; ++j) {
            int ww = wt + j - 1;
            v[j] = (ww < 0 || ww >= WWW) ? 0.f : rowp[(size_t)ww * DI];
        }
        #pragma unroll
        for (int j = 0; j < 8; ++j)
            acc[j] += w0v * v[j] + w1v * v[j + 1] + w2v * v[j + 2];
    }
    size_t outbase = ((size_t)(b * LLEN) + h * WWW + wt) * DI + d;
    #pragma unroll
    for (int j = 0; j < 8; ++j) {
        float aa = acc[j];
        float s = aa * __builtin_amdgcn_rcpf(1.f + __expf(-aa));  // fast SiLU
        xf[outbase + (size_t)j * DI] = s;
    }
}

// ------- Kernels 3/5: fused gather + x_proj + dt_proj + scan ------------
// PHASE 1: emit per-chunk affine summary (Aprod, Bsum).
// PHASE 3: replay with carried-in h, emit ys, atomic-scatter into y.
template <int PHASE>
__global__ __launch_bounds__(256) void k_scan(const float* __restrict__ xf,
                                              const int* __restrict__ sids,
                                              const float* __restrict__ xpw,
                                              const float* __restrict__ dtw,
                                              const float* __restrict__ dtb,
                                              const float* __restrict__ alog,
                                              const float* __restrict__ dsv,
                                              float* __restrict__ cA,
                                              float* __restrict__ cB,
                                              const float* __restrict__ hin,
                                              float* __restrict__ y) {
    __shared__ int sid[PCH];
    __shared__ float xs[DI * 65];       // [d][p] stride 65 (conflict-free all phases)
    __shared__ float xdbl[PCH * 8];     // [p][c] 8 proj channels
    int bid = blockIdx.x;
    int c = bid & (NCH - 1);
    int k = (bid >> 8) & 3;
    int b = bid >> 10;
    int t = threadIdx.x;
    if (t < PCH) sid[t] = sids[k * LLEN + c * PCH + t];
    __syncthreads();
    for (int i = 0; i < 48; ++i) {
        int idx = t + i * 256;          // 0..12287
        int p = idx / DI;
        int d = idx - p * DI;
        xs[d * 65 + p] = xf[((size_t)(b * LLEN) + sid[p]) * DI + d];
    }
    __syncthreads();
    // x_dbl: 512 dot products of length 192; thread (p,co) does channels co, co+4
    {
        int p  = t & 63;
        int co = t >> 6;                // 0..3 (wave-uniform)
        const float* w0 = xpw + (k * 8 + co) * DI;
        const float* w1 = xpw + (k * 8 + co + 4) * DI;
        float a0 = 0.f, a1 = 0.f;
        for (int d = 0; d < DI; ++d) {
            float xv = xs[d * 65 + p];
            a0 += w0[d] * xv;
            a1 += w1[d] * xv;
        }
        xdbl[p * 8 + co]     = a0;
        xdbl[p * 8 + co + 4] = a1;
    }
    __syncthreads();
    if (t < DI) {
        int d = t;
        float wr[6];
        #pragma unroll
        for (int r = 0; r < 6; ++r) wr[r] = dtw[(k * DI + d) * 6 + r];
        float bias = dtb[k * DI + d];
        float A = -__expf(alog[k * DI + d]);
        float Dv = dsv[k * DI + d];
        size_t cidx = ((size_t)((b * KDIR + k) * NCH + c)) * DI + d;
        float Ar = 1.f, Br = 0.f, h = 0.f;
        if (PHASE == 3) h = hin[cidx];
        for (int p = 0; p < PCH; ++p) {
            float s = bias;
            #pragma unroll
            for (int r = 0; r < 6; ++r) s += wr[r] * xdbl[p * 8 + r];
            // fast softplus (native exp/log; guarded for large s)
            float delta = (s > 20.f) ? s : __logf(1.f + __expf(s));
            float a = __expf(delta * A);
            float u = xs[d * 65 + p];
            float bu = delta * xdbl[p * 8 + 6] * u;
            if (PHASE == 1) {
                Ar *= a;
                Br = a * Br + bu;
            } else {
                h = a * h + bu;
                float ys = xdbl[p * 8 + 7] * h + Dv * u;
                atomicAdd(&y[((size_t)(b * LLEN) + sid[p]) * DI + d], ys);
            }
        }
        if (PHASE == 1) { cA[cidx] = Ar; cB[cidx] = Br; }
    }
}

// ------------- Kernel 4: scan of chunk summaries (tiny) -----------------
__global__ __launch_bounds__(192) void k_chunkscan(const float* __restrict__ cA,
                                                   const float* __restrict__ cB,
                                                   float* __restrict__ hin) {
    int bk = blockIdx.x;    // 0..15 = (b,k)
    int d = threadIdx.x;
    float h = 0.f;
    for (int cc = 0; cc < NCH; ++cc) {
        size_t idx = ((size_t)(bk * NCH + cc)) * DI + d;
        hin[idx] = h;
        h = cA[idx] * h + cB[idx];
    }
}

// ------------- Kernel 6: GELU + out_proj (192 -> 96) --------------------
// y: (B, L, 192) -> out: (B, 96, L)
__global__ __launch_bounds__(256) void k_out(const float* __restrict__ y,
                                             const float* __restrict__ wo,
                                             float* __restrict__ out) {
    __shared__ float gy[DI * 65];       // [c][l] stride 65 (pad)
    int bid = blockIdx.x;
    int b = bid >> 8;
    int l0 = (bid & 255) << 6;
    int t = threadIdx.x;
    for (int i = 0; i < 48; ++i) {
        int idx = t + i * 256;          // 0..12287
        int l = idx / DI;
        int cc = idx - l * DI;
        float v = y[((size_t)(b * LLEN) + l0 + l) * DI + cc];
        // fast tanh-GELU: tanh(z) = 1 - 2/(e^{2z}+1)
        float z = 0.7978845608028654f * (v + 0.044715f * v * v * v);
        float e = __expf(2.f * z);
        float th = 1.f - 2.f * __builtin_amdgcn_rcpf(e + 1.f);
        gy[cc * 65 + l] = 0.5f * v * (1.f + th);
    }
    __syncthreads();
    int l = t & 63;
    int og = t >> 6;                    // 0..3, 24 output channels each
    float acc[24];
    #pragma unroll
    for (int i = 0; i < 24; ++i) acc[i] = 0.f;
    int ob = og * 24;
    for (int cc = 0; cc < DI; ++cc) {
        float gv = gy[cc * 65 + l];
        #pragma unroll
        for (int i = 0; i < 24; ++i) acc[i] += wo[(ob + i) * DI + cc] * gv;
    }
    for (int i = 0; i < 24; ++i)
        out[((size_t)(b * CIN) + ob + i) * LLEN + l0 + l] = acc[i];
}

extern "C" void kernel_launch(void* const* d_in, const int* in_sizes, int n_in,
                              void* d_out, int out_size, void* d_ws, size_t ws_size,
                              hipStream_t stream) {
    const float* x        = (const float*)d_in[0];
    const int*   scan_ids = (const int*)d_in[1];
    // d_in[2] inverse_ids: unused (scatter with scan_ids instead)
    const float* in_proj_w = (const float*)d_in[3];
    const float* conv_w    = (const float*)d_in[4];
    const float* conv_b    = (const float*)d_in[5];
    const float* xpw       = (const float*)d_in[6];
    const float* dtw       = (const float*)d_in[7];
    const float* dtb       = (const float*)d_in[8];
    const float* alog      = (const float*)d_in[9];
    const float* dsv       = (const float*)d_in[10];
    const float* wo        = (const float*)d_in[11];
    float* out = (float*)d_out;

    float* ws = (float*)d_ws;
    const size_t NBL = (size_t)BATCH * LLEN * DI;       // 12.58M floats
    const size_t NCK = (size_t)BATCH * KDIR * NCH * DI; // 786432 floats
    float* t0  = ws;            // in_proj output; later reused as y
    float* xf  = t0 + NBL;      // post-conv SiLU activations (B,L,D)
    float* cA  = xf + NBL;
    float* cB  = cA + NCK;
    float* hin = cB + NCK;
    float* y   = t0;            // reuse t0 (dead after k_dwconv)

    k_inproj<<<BATCH * 256, 256, 0, stream>>>(x, in_proj_w, t0);
    k_dwconv<<<BATCH * HH * 16, 192, 0, stream>>>(t0, conv_w, conv_b, xf);
    hipMemsetAsync(y, 0, NBL * sizeof(float), stream);
    k_scan<1><<<BATCH * KDIR * NCH, 256, 0, stream>>>(xf, scan_ids, xpw, dtw, dtb,
                                                      alog, dsv, cA, cB, nullptr, nullptr);
    k_chunkscan<<<BATCH * KDIR, 192, 0, stream>>>(cA, cB, hin);
    k_scan<3><<<BATCH * KDIR * NCH, 256, 0, stream>>>(xf, scan_ids, xpw, dtw, dtb,
                                                      alog, dsv, cA, cB, hin, y);
    k_out<<<BATCH * 256, 256, 0, stream>>>(y, wo, out);
}

// Round 4
// 522.958 us; speedup vs baseline: 1.9456x; 1.3778x over previous
//
#include <hip/hip_runtime.h>
#include <math.h>

#define BATCH 4
#define HH 128
#define WWW 128
#define LLEN (HH*WWW)      // 16384
#define CIN 96
#define DI 192
#define KDIR 4
#define NCH 512            // number of chunks
#define PCH 32             // chunk length  (NCH*PCH == LLEN)

// ---------------- Kernel 1: in_proj (1x1 conv, 96 -> 192) ----------------
// x: (B, 96, L) channel-major.  t0: (B, L, 192) row-major rows.
__global__ __launch_bounds__(256) void k_inproj(const float* __restrict__ x,
                                                const float* __restrict__ w,
                                                float* __restrict__ t0) {
    __shared__ float xin[CIN * 64];     // [c][l] stride 64
    __shared__ float wt[CIN * 65];      // [c][o] stride 65 (pad)
    int bid = blockIdx.x;
    int b = bid >> 8;                   // 256 l-tiles per batch
    int l0 = (bid & 255) << 6;
    int t = threadIdx.x;
    for (int i = 0; i < 24; ++i) {
        int idx = t + i * 256;          // 0..6143
        int c = idx >> 6, l = idx & 63;
        xin[c * 64 + l] = x[((size_t)(b * CIN + c)) * LLEN + l0 + l];
    }
    int o_lane = t & 63;
    int lgrp = t >> 6;                  // 0..3
    for (int ot = 0; ot < 3; ++ot) {
        __syncthreads();
        for (int i = 0; i < 24; ++i) {
            int idx = t + i * 256;      // 0..6143 over (o,c), c fastest
            int o = idx / 96, c = idx - o * 96;
            wt[c * 65 + o] = w[(ot * 64 + o) * 96 + c];
        }
        __syncthreads();
        float4 acc4[4];
        #pragma unroll
        for (int i = 0; i < 4; ++i) acc4[i] = make_float4(0.f, 0.f, 0.f, 0.f);
        int lb = lgrp * 16;
        for (int c = 0; c < CIN; ++c) {
            float wv = wt[c * 65 + o_lane];
            const float4* xv = reinterpret_cast<const float4*>(&xin[c * 64 + lb]);
            #pragma unroll
            for (int i = 0; i < 4; ++i) {
                float4 xx = xv[i];      // broadcast b128
                acc4[i].x += wv * xx.x; acc4[i].y += wv * xx.y;
                acc4[i].z += wv * xx.z; acc4[i].w += wv * xx.w;
            }
        }
        int o = ot * 64 + o_lane;
        #pragma unroll
        for (int i = 0; i < 4; ++i) {
            t0[((size_t)(b * LLEN) + l0 + lb + i * 4 + 0) * DI + o] = acc4[i].x;
            t0[((size_t)(b * LLEN) + l0 + lb + i * 4 + 1) * DI + o] = acc4[i].y;
            t0[((size_t)(b * LLEN) + l0 + lb + i * 4 + 2) * DI + o] = acc4[i].z;
            t0[((size_t)(b * LLEN) + l0 + lb + i * 4 + 3) * DI + o] = acc4[i].w;
        }
    }
}

// ------------- Kernel 2: depthwise 3x3 conv + bias + SiLU ---------------
__global__ __launch_bounds__(192) void k_dwconv(const float* __restrict__ t0,
                                                const float* __restrict__ cw,
                                                const float* __restrict__ cb,
                                                float* __restrict__ xf) {
    int bid = blockIdx.x;
    int wt = (bid & 15) << 3;           // 16 tiles of 8 along w
    int h  = (bid >> 4) & (HH - 1);
    int b  = bid >> 11;
    int d  = threadIdx.x;
    float acc[8];
    float bias = cb[d];
    #pragma unroll
    for (int j = 0; j < 8; ++j) acc[j] = bias;
    #pragma unroll
    for (int kh = 0; kh < 3; ++kh) {
        int hh = h + kh - 1;
        if (hh < 0 || hh >= HH) continue;
        float w0v = cw[d * 9 + kh * 3 + 0];
        float w1v = cw[d * 9 + kh * 3 + 1];
        float w2v = cw[d * 9 + kh * 3 + 2];
        const float* rowp = t0 + ((size_t)(b * LLEN) + hh * WWW) * DI + d;
        float v[10];
        #pragma unroll
        for (int j = 0; j < 10; ++j) {
            int ww = wt + j - 1;
            v[j] = (ww < 0 || ww >= WWW) ? 0.f : rowp[(size_t)ww * DI];
        }
        #pragma unroll
        for (int j = 0; j < 8; ++j)
            acc[j] += w0v * v[j] + w1v * v[j + 1] + w2v * v[j + 2];
    }
    size_t outbase = ((size_t)(b * LLEN) + h * WWW + wt) * DI + d;
    #pragma unroll
    for (int j = 0; j < 8; ++j) {
        float aa = acc[j];
        float s = aa * __builtin_amdgcn_rcpf(1.f + __expf(-aa));  // fast SiLU
        xf[outbase + (size_t)j * DI] = s;
    }
}

// ---- Kernel 3: phase-1 — fused gather + x_proj + chunk-summary scan ----
// Writes xdblg (8 proj channels per position) + per-chunk (cA,cB).
__global__ __launch_bounds__(256) void k_scan1(const float* __restrict__ xf,
                                               const int* __restrict__ sids,
                                               const float* __restrict__ xpw,
                                               const float* __restrict__ dtw,
                                               const float* __restrict__ dtb,
                                               const float* __restrict__ alog,
                                               const float* __restrict__ dsv,
                                               float* __restrict__ cA,
                                               float* __restrict__ cB,
                                               float* __restrict__ xdblg) {
    __shared__ float part[32 * 4 * 9];  // [p][w][co] stride 9 (pad)
    __shared__ float xdbl[PCH * 8];     // [p][co]
    __shared__ int sid[PCH];
    int bid = blockIdx.x;
    int c = bid & (NCH - 1);
    int k = (bid >> 9) & 3;
    int b = bid >> 11;
    int t = threadIdx.x;
    if (t < PCH) sid[t] = sids[k * LLEN + c * PCH + t];
    __syncthreads();
    // fused gather + partial dots: thread (p, s): 24-float segment of row sid[p]
    {
        int p = t & 31, s = t >> 5;     // s in 0..7
        const float* row = xf + ((size_t)(b * LLEN) + sid[p]) * DI + s * 24;
        float4 v[6];
        #pragma unroll
        for (int j = 0; j < 6; ++j) v[j] = reinterpret_cast<const float4*>(row)[j];
        const float* wbase = xpw + (size_t)k * 8 * DI + s * 24;
        float pd[8];
        #pragma unroll
        for (int co = 0; co < 8; ++co) {
            const float4* w4 = reinterpret_cast<const float4*>(wbase + co * DI);
            float a0 = 0.f;
            #pragma unroll
            for (int j = 0; j < 6; ++j) {
                float4 wv = w4[j];
                a0 += wv.x * v[j].x + wv.y * v[j].y + wv.z * v[j].z + wv.w * v[j].w;
            }
            pd[co] = a0;
        }
        // combine s with s^1 (lanes l and l^32 within the wave64)
        #pragma unroll
        for (int co = 0; co < 8; ++co) pd[co] += __shfl_xor(pd[co], 32);
        if ((s & 1) == 0) {
            int wq = s >> 1;            // 0..3
            #pragma unroll
            for (int co = 0; co < 8; ++co) part[(p * 4 + wq) * 9 + co] = pd[co];
        }
    }
    __syncthreads();
    // reduce 4 partials -> xdbl (LDS + global)
    {
        int p = t >> 3, co = t & 7;
        float s = part[(p * 4 + 0) * 9 + co] + part[(p * 4 + 1) * 9 + co] +
                  part[(p * 4 + 2) * 9 + co] + part[(p * 4 + 3) * 9 + co];
        xdbl[p * 8 + co] = s;
        xdblg[(size_t)bid * (PCH * 8) + t] = s;   // t == p*8+co
    }
    __syncthreads();
    if (t < DI) {
        int d = t;
        float wr[6];
        #pragma unroll
        for (int r = 0; r < 6; ++r) wr[r] = dtw[(k * DI + d) * 6 + r];
        float bias = dtb[k * DI + d];
        float A = -__expf(alog[k * DI + d]);
        float Ar = 1.f, Br = 0.f;
        const float4* xd4 = reinterpret_cast<const float4*>(xdbl);
        const float* ubase = xf + (size_t)(b * LLEN) * DI + d;
        #pragma unroll 2
        for (int p = 0; p < PCH; ++p) {
            float4 x0 = xd4[p * 2], x1 = xd4[p * 2 + 1];   // broadcast b128
            float s = bias + wr[0] * x0.x + wr[1] * x0.y + wr[2] * x0.z +
                      wr[3] * x0.w + wr[4] * x1.x + wr[5] * x1.y;
            float delta = (s > 20.f) ? s : __logf(1.f + __expf(s));
            float a = __expf(delta * A);
            float u = ubase[(size_t)sid[p] * DI];          // coalesced global (L2/L3)
            float bu = delta * x1.z * u;
            Br = a * Br + bu;
            Ar *= a;
        }
        cA[(size_t)bid * DI + d] = Ar;
        cB[(size_t)bid * DI + d] = Br;
    }
}

// ---- chunk-summary scans (3 tiny kernels; NSEG=16 segs of 32 chunks) ----
__global__ __launch_bounds__(192) void k_cs1(const float* __restrict__ cA,
                                             const float* __restrict__ cB,
                                             float* __restrict__ segA,
                                             float* __restrict__ segB) {
    int g = blockIdx.x;                 // bk*16 + seg
    int d = threadIdx.x;
    size_t base = (size_t)g * 32 * DI + d;
    float A = 1.f, Bv = 0.f;
    for (int cc = 0; cc < 32; ++cc) {
        float a = cA[base + (size_t)cc * DI];
        float bb = cB[base + (size_t)cc * DI];
        Bv = a * Bv + bb;
        A *= a;
    }
    segA[(size_t)g * DI + d] = A;
    segB[(size_t)g * DI + d] = Bv;
}
__global__ __launch_bounds__(192) void k_cs2(const float* __restrict__ segA,
                                             const float* __restrict__ segB,
                                             float* __restrict__ hseg) {
    int bk = blockIdx.x;                // 0..15
    int d = threadIdx.x;
    float h = 0.f;
    for (int seg = 0; seg < 16; ++seg) {
        size_t idx = (size_t)(bk * 16 + seg) * DI + d;
        hseg[idx] = h;
        h = segA[idx] * h + segB[idx];
    }
}
// writes per-chunk h0 INTO cB (aliased as hin), reading old cB first
__global__ __launch_bounds__(192) void k_cs3(const float* __restrict__ cA,
                                             float* __restrict__ cB,
                                             const float* __restrict__ hseg) {
    int g = blockIdx.x;                 // bk*16 + seg
    int d = threadIdx.x;
    float h = hseg[(size_t)g * DI + d];
    size_t base = (size_t)g * 32 * DI + d;
    for (int cc = 0; cc < 32; ++cc) {
        size_t ix = base + (size_t)cc * DI;
        float a = cA[ix];
        float bb = cB[ix];
        cB[ix] = h;                     // hin for this chunk
        h = a * h + bb;
    }
}

// ---- Kernel 5: phase-3 — scan replay + atomic scatter (no projections) --
__global__ __launch_bounds__(192) void k_scan3(const float* __restrict__ xf,
                                               const int* __restrict__ sids,
                                               const float* __restrict__ dtw,
                                               const float* __restrict__ dtb,
                                               const float* __restrict__ alog,
                                               const float* __restrict__ dsv,
                                               const float* __restrict__ hin,
                                               const float* __restrict__ xdblg,
                                               float* __restrict__ y) {
    __shared__ float xdbl[PCH * 8];
    __shared__ int sid[PCH];
    int bid = blockIdx.x;
    int c = bid & (NCH - 1);
    int k = (bid >> 9) & 3;
    int b = bid >> 11;
    int t = threadIdx.x;
    if (t < PCH) sid[t] = sids[k * LLEN + c * PCH + t];
    if (t < 64) {
        reinterpret_cast<float4*>(xdbl)[t] =
            reinterpret_cast<const float4*>(xdblg + (size_t)bid * (PCH * 8))[t];
    }
    __syncthreads();
    int d = t;
    float wr[6];
    #pragma unroll
    for (int r = 0; r < 6; ++r) wr[r] = dtw[(k * DI + d) * 6 + r];
    float bias = dtb[k * DI + d];
    float A = -__expf(alog[k * DI + d]);
    float Dv = dsv[k * DI + d];
    float h = hin[(size_t)bid * DI + d];
    const float4* xd4 = reinterpret_cast<const float4*>(xdbl);
    const float* ubase = xf + (size_t)(b * LLEN) * DI + d;
    float* ybase = y + (size_t)(b * LLEN) * DI + d;
    #pragma unroll 2
    for (int p = 0; p < PCH; ++p) {
        float4 x0 = xd4[p * 2], x1 = xd4[p * 2 + 1];
        float s = bias + wr[0] * x0.x + wr[1] * x0.y + wr[2] * x0.z +
                  wr[3] * x0.w + wr[4] * x1.x + wr[5] * x1.y;
        float delta = (s > 20.f) ? s : __logf(1.f + __expf(s));
        float a = __expf(delta * A);
        float u = ubase[(size_t)sid[p] * DI];
        float bu = delta * x1.z * u;
        h = a * h + bu;
        float ys = x1.w * h + Dv * u;
        atomicAdd(&ybase[(size_t)sid[p] * DI], ys);
    }
}

// ------------- Kernel 6: GELU + out_proj (192 -> 96) --------------------
__global__ __launch_bounds__(256) void k_out(const float* __restrict__ y,
                                             const float* __restrict__ wo,
                                             float* __restrict__ out) {
    __shared__ float gy[DI * 65];       // [c][l] stride 65 (pad)
    int bid = blockIdx.x;
    int b = bid >> 8;
    int l0 = (bid & 255) << 6;
    int t = threadIdx.x;
    for (int i = 0; i < 48; ++i) {
        int idx = t + i * 256;          // 0..12287
        int l = idx / DI;
        int cc = idx - l * DI;
        float v = y[((size_t)(b * LLEN) + l0 + l) * DI + cc];
        float z = 0.7978845608028654f * (v + 0.044715f * v * v * v);
        float e = __expf(2.f * z);
        float th = 1.f - 2.f * __builtin_amdgcn_rcpf(e + 1.f);
        gy[cc * 65 + l] = 0.5f * v * (1.f + th);
    }
    __syncthreads();
    // thread = (lq, oh): 4 l's x 6 o's
    int lq = t & 15, oh = t >> 4;
    float acc[6][4];
    #pragma unroll
    for (int i = 0; i < 6; ++i)
        #pragma unroll
        for (int e = 0; e < 4; ++e) acc[i][e] = 0.f;
    for (int cc = 0; cc < DI; cc += 4) {
        float4 wv[6];
        #pragma unroll
        for (int i = 0; i < 6; ++i)
            wv[i] = *reinterpret_cast<const float4*>(&wo[(oh * 6 + i) * DI + cc]);
        float g[4][4];                  // [e_l][e_cc]
        #pragma unroll
        for (int el = 0; el < 4; ++el) {
            g[el][0] = gy[(cc + 0) * 65 + lq * 4 + el];
            g[el][1] = gy[(cc + 1) * 65 + lq * 4 + el];
            g[el][2] = gy[(cc + 2) * 65 + lq * 4 + el];
            g[el][3] = gy[(cc + 3) * 65 + lq * 4 + el];
        }
        #pragma unroll
        for (int i = 0; i < 6; ++i)
            #pragma unroll
            for (int el = 0; el < 4; ++el)
                acc[i][el] += wv[i].x * g[el][0] + wv[i].y * g[el][1] +
                              wv[i].z * g[el][2] + wv[i].w * g[el][3];
    }
    #pragma unroll
    for (int i = 0; i < 6; ++i) {
        int o = oh * 6 + i;
        float4 st = make_float4(acc[i][0], acc[i][1], acc[i][2], acc[i][3]);
        *reinterpret_cast<float4*>(&out[((size_t)(b * CIN) + o) * LLEN + l0 + lq * 4]) = st;
    }
}

extern "C" void kernel_launch(void* const* d_in, const int* in_sizes, int n_in,
                              void* d_out, int out_size, void* d_ws, size_t ws_size,
                              hipStream_t stream) {
    const float* x        = (const float*)d_in[0];
    const int*   scan_ids = (const int*)d_in[1];
    const float* in_proj_w = (const float*)d_in[3];
    const float* conv_w    = (const float*)d_in[4];
    const float* conv_b    = (const float*)d_in[5];
    const float* xpw       = (const float*)d_in[6];
    const float* dtw       = (const float*)d_in[7];
    const float* dtb       = (const float*)d_in[8];
    const float* alog      = (const float*)d_in[9];
    const float* dsv       = (const float*)d_in[10];
    const float* wo        = (const float*)d_in[11];
    float* out = (float*)d_out;

    float* ws = (float*)d_ws;
    const size_t NBL  = (size_t)BATCH * LLEN * DI;        // 12.58M floats
    const size_t NCK  = (size_t)BATCH * KDIR * NCH * DI;  // 1.57M floats
    const size_t NXD  = (size_t)BATCH * KDIR * LLEN * 8;  // 2.10M floats
    const size_t NSG  = (size_t)BATCH * KDIR * 16 * DI;   // 49152 floats
    float* t0    = ws;             // in_proj out; later reused as y
    float* xf    = t0 + NBL;
    float* xdblg = xf + NBL;
    float* cA    = xdblg + NXD;
    float* cB    = cA + NCK;       // becomes hin after k_cs3
    float* segA  = cB + NCK;
    float* segB  = segA + NSG;
    float* hseg  = segB + NSG;
    float* y     = t0;

    k_inproj<<<BATCH * 256, 256, 0, stream>>>(x, in_proj_w, t0);
    k_dwconv<<<BATCH * HH * 16, 192, 0, stream>>>(t0, conv_w, conv_b, xf);
    hipMemsetAsync(y, 0, NBL * sizeof(float), stream);
    k_scan1<<<BATCH * KDIR * NCH, 256, 0, stream>>>(xf, scan_ids, xpw, dtw, dtb,
                                                    alog, dsv, cA, cB, xdblg);
    k_cs1<<<BATCH * KDIR * 16, 192, 0, stream>>>(cA, cB, segA, segB);
    k_cs2<<<BATCH * KDIR, 192, 0, stream>>>(segA, segB, hseg);
    k_cs3<<<BATCH * KDIR * 16, 192, 0, stream>>>(cA, cB, hseg);
    k_scan3<<<BATCH * KDIR * NCH, 192, 0, stream>>>(xf, scan_ids, dtw, dtb,
                                                    alog, dsv, cB, xdblg, y);
    k_out<<<BATCH * 256, 256, 0, stream>>>(y, wo, out);
}

// Round 6
// 518.999 us; speedup vs baseline: 1.9605x; 1.0076x over previous
//
#include <hip/hip_runtime.h>
#include <math.h>

#define BATCH 4
#define HH 128
#define WWW 128
#define LLEN (HH*WWW)      // 16384
#define CIN 96
#define DI 192
#define KDIR 4
#define NCH 512            // number of chunks
#define PCH 32             // chunk length  (NCH*PCH == LLEN)

// ---------------- Kernel 1: in_proj (1x1 conv, 96 -> 192) ----------------
// x: (B, 96, L) channel-major.  t0: (B, L, 192) row-major rows.
__global__ __launch_bounds__(256) void k_inproj(const float* __restrict__ x,
                                                const float* __restrict__ w,
                                                float* __restrict__ t0) {
    __shared__ float xin[CIN * 64];     // [c][l] stride 64
    __shared__ float wt[CIN * 65];      // [c][o] stride 65 (pad)
    int bid = blockIdx.x;
    int b = bid >> 8;                   // 256 l-tiles per batch
    int l0 = (bid & 255) << 6;
    int t = threadIdx.x;
    for (int i = 0; i < 24; ++i) {
        int idx = t + i * 256;          // 0..6143
        int c = idx >> 6, l = idx & 63;
        xin[c * 64 + l] = x[((size_t)(b * CIN + c)) * LLEN + l0 + l];
    }
    int o_lane = t & 63;
    int lgrp = t >> 6;                  // 0..3
    for (int ot = 0; ot < 3; ++ot) {
        __syncthreads();
        for (int i = 0; i < 24; ++i) {
            int idx = t + i * 256;      // 0..6143 over (o,c), c fastest
            int o = idx / 96, c = idx - o * 96;
            wt[c * 65 + o] = w[(ot * 64 + o) * 96 + c];
        }
        __syncthreads();
        float4 acc4[4];
        #pragma unroll
        for (int i = 0; i < 4; ++i) acc4[i] = make_float4(0.f, 0.f, 0.f, 0.f);
        int lb = lgrp * 16;
        for (int c = 0; c < CIN; ++c) {
            float wv = wt[c * 65 + o_lane];
            const float4* xv = reinterpret_cast<const float4*>(&xin[c * 64 + lb]);
            #pragma unroll
            for (int i = 0; i < 4; ++i) {
                float4 xx = xv[i];      // broadcast b128
                acc4[i].x += wv * xx.x; acc4[i].y += wv * xx.y;
                acc4[i].z += wv * xx.z; acc4[i].w += wv * xx.w;
            }
        }
        int o = ot * 64 + o_lane;
        #pragma unroll
        for (int i = 0; i < 4; ++i) {
            t0[((size_t)(b * LLEN) + l0 + lb + i * 4 + 0) * DI + o] = acc4[i].x;
            t0[((size_t)(b * LLEN) + l0 + lb + i * 4 + 1) * DI + o] = acc4[i].y;
            t0[((size_t)(b * LLEN) + l0 + lb + i * 4 + 2) * DI + o] = acc4[i].z;
            t0[((size_t)(b * LLEN) + l0 + lb + i * 4 + 3) * DI + o] = acc4[i].w;
        }
    }
}

// ------------- Kernel 2: depthwise 3x3 conv + bias + SiLU ---------------
__global__ __launch_bounds__(192) void k_dwconv(const float* __restrict__ t0,
                                                const float* __restrict__ cw,
                                                const float* __restrict__ cb,
                                                float* __restrict__ xf) {
    int bid = blockIdx.x;
    int wt = (bid & 15) << 3;           // 16 tiles of 8 along w
    int h  = (bid >> 4) & (HH - 1);
    int b  = bid >> 11;
    int d  = threadIdx.x;
    float acc[8];
    float bias = cb[d];
    #pragma unroll
    for (int j = 0; j < 8; ++j) acc[j] = bias;
    #pragma unroll
    for (int kh = 0; kh < 3; ++kh) {
        int hh = h + kh - 1;
        if (hh < 0 || hh >= HH) continue;
        float w0v = cw[d * 9 + kh * 3 + 0];
        float w1v = cw[d * 9 + kh * 3 + 1];
        float w2v = cw[d * 9 + kh * 3 + 2];
        const float* rowp = t0 + ((size_t)(b * LLEN) + hh * WWW) * DI + d;
        float v[10];
        #pragma unroll
        for (int j = 0; j < 10; ++j) {
            int ww = wt + j - 1;
            v[j] = (ww < 0 || ww >= WWW) ? 0.f : rowp[(size_t)ww * DI];
        }
        #pragma unroll
        for (int j = 0; j < 8; ++j)
            acc[j] += w0v * v[j] + w1v * v[j + 1] + w2v * v[j + 2];
    }
    size_t outbase = ((size_t)(b * LLEN) + h * WWW + wt) * DI + d;
    #pragma unroll
    for (int j = 0; j < 8; ++j) {
        float aa = acc[j];
        float s = aa * __builtin_amdgcn_rcpf(1.f + __expf(-aa));  // fast SiLU
        xf[outbase + (size_t)j * DI] = s;
    }
}

// ---- Kernel 3: phase-1 — fused gather + x_proj + chunk-summary scan ----
// Writes xdblg (8 proj channels per position) + per-chunk (cA,cB).
__global__ __launch_bounds__(256) void k_scan1(const float* __restrict__ xf,
                                               const int* __restrict__ sids,
                                               const float* __restrict__ xpw,
                                               const float* __restrict__ dtw,
                                               const float* __restrict__ dtb,
                                               const float* __restrict__ alog,
                                               const float* __restrict__ dsv,
                                               float* __restrict__ cA,
                                               float* __restrict__ cB,
                                               float* __restrict__ xdblg) {
    __shared__ float part[32 * 4 * 9];  // [p][w][co] stride 9 (pad)
    __shared__ float xdbl[PCH * 8];     // [p][co]
    __shared__ int sid[PCH];
    int bid = blockIdx.x;
    int c = bid & (NCH - 1);
    int k = (bid >> 9) & 3;
    int b = bid >> 11;
    int t = threadIdx.x;
    if (t < PCH) sid[t] = sids[k * LLEN + c * PCH + t];
    __syncthreads();
    // fused gather + partial dots: thread (p, s): 24-float segment of row sid[p]
    {
        int p = t & 31, s = t >> 5;     // s in 0..7
        const float* row = xf + ((size_t)(b * LLEN) + sid[p]) * DI + s * 24;
        float4 v[6];
        #pragma unroll
        for (int j = 0; j < 6; ++j) v[j] = reinterpret_cast<const float4*>(row)[j];
        const float* wbase = xpw + (size_t)k * 8 * DI + s * 24;
        float pd[8];
        #pragma unroll
        for (int co = 0; co < 8; ++co) {
            const float4* w4 = reinterpret_cast<const float4*>(wbase + co * DI);
            float a0 = 0.f;
            #pragma unroll
            for (int j = 0; j < 6; ++j) {
                float4 wv = w4[j];
                a0 += wv.x * v[j].x + wv.y * v[j].y + wv.z * v[j].z + wv.w * v[j].w;
            }
            pd[co] = a0;
        }
        // combine s with s^1 (lanes l and l^32 within the wave64)
        #pragma unroll
        for (int co = 0; co < 8; ++co) pd[co] += __shfl_xor(pd[co], 32);
        if ((s & 1) == 0) {
            int wq = s >> 1;            // 0..3
            #pragma unroll
            for (int co = 0; co < 8; ++co) part[(p * 4 + wq) * 9 + co] = pd[co];
        }
    }
    __syncthreads();
    // reduce 4 partials -> xdbl (LDS + global)
    {
        int p = t >> 3, co = t & 7;
        float s = part[(p * 4 + 0) * 9 + co] + part[(p * 4 + 1) * 9 + co] +
                  part[(p * 4 + 2) * 9 + co] + part[(p * 4 + 3) * 9 + co];
        xdbl[p * 8 + co] = s;
        xdblg[(size_t)bid * (PCH * 8) + t] = s;   // t == p*8+co
    }
    __syncthreads();
    if (t < DI) {
        int d = t;
        const float* ubase = xf + (size_t)(b * LLEN) * DI + d;
        // preload all u values (batch the latency; no dependent stalls in loop)
        float uv[PCH];
        #pragma unroll
        for (int p = 0; p < PCH; ++p) uv[p] = ubase[(size_t)sid[p] * DI];
        float wr[6];
        #pragma unroll
        for (int r = 0; r < 6; ++r) wr[r] = dtw[(k * DI + d) * 6 + r];
        float bias = dtb[k * DI + d];
        float A = -__expf(alog[k * DI + d]);
        float Ar = 1.f, Br = 0.f;
        const float4* xd4 = reinterpret_cast<const float4*>(xdbl);
        #pragma unroll
        for (int p = 0; p < PCH; ++p) {
            float4 x0 = xd4[p * 2], x1 = xd4[p * 2 + 1];   // broadcast b128
            float s = bias + wr[0] * x0.x + wr[1] * x0.y + wr[2] * x0.z +
                      wr[3] * x0.w + wr[4] * x1.x + wr[5] * x1.y;
            float delta = (s > 20.f) ? s : __logf(1.f + __expf(s));
            float a = __expf(delta * A);
            float bu = delta * x1.z * uv[p];
            Br = a * Br + bu;
            Ar *= a;
        }
        cA[(size_t)bid * DI + d] = Ar;
        cB[(size_t)bid * DI + d] = Br;
    }
}

// ---- chunk-summary scans (3 tiny kernels; NSEG=16 segs of 32 chunks) ----
__global__ __launch_bounds__(192) void k_cs1(const float* __restrict__ cA,
                                             const float* __restrict__ cB,
                                             float* __restrict__ segA,
                                             float* __restrict__ segB) {
    int g = blockIdx.x;                 // bk*16 + seg
    int d = threadIdx.x;
    size_t base = (size_t)g * 32 * DI + d;
    float A = 1.f, Bv = 0.f;
    for (int cc = 0; cc < 32; ++cc) {
        float a = cA[base + (size_t)cc * DI];
        float bb = cB[base + (size_t)cc * DI];
        Bv = a * Bv + bb;
        A *= a;
    }
    segA[(size_t)g * DI + d] = A;
    segB[(size_t)g * DI + d] = Bv;
}
__global__ __launch_bounds__(192) void k_cs2(const float* __restrict__ segA,
                                             const float* __restrict__ segB,
                                             float* __restrict__ hseg) {
    int bk = blockIdx.x;                // 0..15
    int d = threadIdx.x;
    float h = 0.f;
    for (int seg = 0; seg < 16; ++seg) {
        size_t idx = (size_t)(bk * 16 + seg) * DI + d;
        hseg[idx] = h;
        h = segA[idx] * h + segB[idx];
    }
}
// writes per-chunk h0 INTO cB (aliased as hin), reading old cB first
__global__ __launch_bounds__(192) void k_cs3(const float* __restrict__ cA,
                                             float* __restrict__ cB,
                                             const float* __restrict__ hseg) {
    int g = blockIdx.x;                 // bk*16 + seg
    int d = threadIdx.x;
    float h = hseg[(size_t)g * DI + d];
    size_t base = (size_t)g * 32 * DI + d;
    for (int cc = 0; cc < 32; ++cc) {
        size_t ix = base + (size_t)cc * DI;
        float a = cA[ix];
        float bb = cB[ix];
        cB[ix] = h;                     // hin for this chunk
        h = a * h + bb;
    }
}

// ---- Kernel 5: phase-3 — scan replay + atomic scatter (no projections) --
__global__ __launch_bounds__(192) void k_scan3(const float* __restrict__ xf,
                                               const int* __restrict__ sids,
                                               const float* __restrict__ dtw,
                                               const float* __restrict__ dtb,
                                               const float* __restrict__ alog,
                                               const float* __restrict__ dsv,
                                               const float* __restrict__ hin,
                                               const float* __restrict__ xdblg,
                                               float* __restrict__ y) {
    __shared__ float xdbl[PCH * 8];
    __shared__ int sid[PCH];
    int bid = blockIdx.x;
    int c = bid & (NCH - 1);
    int k = (bid >> 9) & 3;
    int b = bid >> 11;
    int t = threadIdx.x;
    if (t < PCH) sid[t] = sids[k * LLEN + c * PCH + t];
    if (t < 64) {
        reinterpret_cast<float4*>(xdbl)[t] =
            reinterpret_cast<const float4*>(xdblg + (size_t)bid * (PCH * 8))[t];
    }
    __syncthreads();
    int d = t;
    const float* ubase = xf + (size_t)(b * LLEN) * DI + d;
    // ALL u loads issued before any atomic: vmcnt waits for u never drain atomics.
    float uv[PCH];
    #pragma unroll
    for (int p = 0; p < PCH; ++p) uv[p] = ubase[(size_t)sid[p] * DI];
    float wr[6];
    #pragma unroll
    for (int r = 0; r < 6; ++r) wr[r] = dtw[(k * DI + d) * 6 + r];
    float bias = dtb[k * DI + d];
    float A = -__expf(alog[k * DI + d]);
    float Dv = dsv[k * DI + d];
    float h = hin[(size_t)bid * DI + d];
    const float4* xd4 = reinterpret_cast<const float4*>(xdbl);
    float* ybase = y + (size_t)(b * LLEN) * DI + d;
    #pragma unroll
    for (int p = 0; p < PCH; ++p) {
        float4 x0 = xd4[p * 2], x1 = xd4[p * 2 + 1];
        float s = bias + wr[0] * x0.x + wr[1] * x0.y + wr[2] * x0.z +
                  wr[3] * x0.w + wr[4] * x1.x + wr[5] * x1.y;
        float delta = (s > 20.f) ? s : __logf(1.f + __expf(s));
        float a = __expf(delta * A);
        float bu = delta * x1.z * uv[p];
        h = a * h + bu;
        float ys = x1.w * h + Dv * uv[p];
        atomicAdd(&ybase[(size_t)sid[p] * DI], ys);
    }
}

// ------------- Kernel 6: GELU + out_proj (192 -> 96) --------------------
__global__ __launch_bounds__(256) void k_out(const float* __restrict__ y,
                                             const float* __restrict__ wo,
                                             float* __restrict__ out) {
    __shared__ float gy[DI * 65];       // [c][l] stride 65 (pad)
    int bid = blockIdx.x;
    int b = bid >> 8;
    int l0 = (bid & 255) << 6;
    int t = threadIdx.x;
    for (int i = 0; i < 48; ++i) {
        int idx = t + i * 256;          // 0..12287
        int l = idx / DI;
        int cc = idx - l * DI;
        float v = y[((size_t)(b * LLEN) + l0 + l) * DI + cc];
        float z = 0.7978845608028654f * (v + 0.044715f * v * v * v);
        float e = __expf(2.f * z);
        float th = 1.f - 2.f * __builtin_amdgcn_rcpf(e + 1.f);
        gy[cc * 65 + l] = 0.5f * v * (1.f + th);
    }
    __syncthreads();
    // thread = (lq, oh): 4 l's x 6 o's
    int lq = t & 15, oh = t >> 4;
    float acc[6][4];
    #pragma unroll
    for (int i = 0; i < 6; ++i)
        #pragma unroll
        for (int e = 0; e < 4; ++e) acc[i][e] = 0.f;
    for (int cc = 0; cc < DI; cc += 4) {
        float4 wv[6];
        #pragma unroll
        for (int i = 0; i < 6; ++i)
            wv[i] = *reinterpret_cast<const float4*>(&wo[(oh * 6 + i) * DI + cc]);
        float g[4][4];                  // [e_l][e_cc]
        #pragma unroll
        for (int el = 0; el < 4; ++el) {
            g[el][0] = gy[(cc + 0) * 65 + lq * 4 + el];
            g[el][1] = gy[(cc + 1) * 65 + lq * 4 + el];
            g[el][2] = gy[(cc + 2) * 65 + lq * 4 + el];
            g[el][3] = gy[(cc + 3) * 65 + lq * 4 + el];
        }
        #pragma unroll
        for (int i = 0; i < 6; ++i)
            #pragma unroll
            for (int el = 0; el < 4; ++el)
                acc[i][el] += wv[i].x * g[el][0] + wv[i].y * g[el][1] +
                              wv[i].z * g[el][2] + wv[i].w * g[el][3];
    }
    #pragma unroll
    for (int i = 0; i < 6; ++i) {
        int o = oh * 6 + i;
        float4 st = make_float4(acc[i][0], acc[i][1], acc[i][2], acc[i][3]);
        *reinterpret_cast<float4*>(&out[((size_t)(b * CIN) + o) * LLEN + l0 + lq * 4]) = st;
    }
}

extern "C" void kernel_launch(void* const* d_in, const int* in_sizes, int n_in,
                              void* d_out, int out_size, void* d_ws, size_t ws_size,
                              hipStream_t stream) {
    const float* x        = (const float*)d_in[0];
    const int*   scan_ids = (const int*)d_in[1];
    const float* in_proj_w = (const float*)d_in[3];
    const float* conv_w    = (const float*)d_in[4];
    const float* conv_b    = (const float*)d_in[5];
    const float* xpw       = (const float*)d_in[6];
    const float* dtw       = (const float*)d_in[7];
    const float* dtb       = (const float*)d_in[8];
    const float* alog      = (const float*)d_in[9];
    const float* dsv       = (const float*)d_in[10];
    const float* wo        = (const float*)d_in[11];
    float* out = (float*)d_out;

    float* ws = (float*)d_ws;
    const size_t NBL  = (size_t)BATCH * LLEN * DI;        // 12.58M floats
    const size_t NCK  = (size_t)BATCH * KDIR * NCH * DI;  // 1.57M floats
    const size_t NXD  = (size_t)BATCH * KDIR * LLEN * 8;  // 2.10M floats
    const size_t NSG  = (size_t)BATCH * KDIR * 16 * DI;   // 49152 floats
    float* t0    = ws;             // in_proj out; later reused as y
    float* xf    = t0 + NBL;
    float* xdblg = xf + NBL;
    float* cA    = xdblg + NXD;
    float* cB    = cA + NCK;       // becomes hin after k_cs3
    float* segA  = cB + NCK;
    float* segB  = segA + NSG;
    float* hseg  = segB + NSG;
    float* y     = t0;

    k_inproj<<<BATCH * 256, 256, 0, stream>>>(x, in_proj_w, t0);
    k_dwconv<<<BATCH * HH * 16, 192, 0, stream>>>(t0, conv_w, conv_b, xf);
    hipMemsetAsync(y, 0, NBL * sizeof(float), stream);
    k_scan1<<<BATCH * KDIR * NCH, 256, 0, stream>>>(xf, scan_ids, xpw, dtw, dtb,
                                                    alog, dsv, cA, cB, xdblg);
    k_cs1<<<BATCH * KDIR * 16, 192, 0, stream>>>(cA, cB, segA, segB);
    k_cs2<<<BATCH * KDIR, 192, 0, stream>>>(segA, segB, hseg);
    k_cs3<<<BATCH * KDIR * 16, 192, 0, stream>>>(cA, cB, hseg);
    k_scan3<<<BATCH * KDIR * NCH, 192, 0, stream>>>(xf, scan_ids, dtw, dtb,
                                                    alog, dsv, cB, xdblg, y);
    k_out<<<BATCH * 256, 256, 0, stream>>>(y, wo, out);
}

// Round 7
// 441.977 us; speedup vs baseline: 2.3021x; 1.1743x over previous
//
#include <hip/hip_runtime.h>
#include <math.h>

#define BATCH 4
#define HH 128
#define WWW 128
#define LLEN (HH*WWW)      // 16384
#define CIN 96
#define DI 192
#define KDIR 4
#define NCH 512            // number of chunks
#define PCH 32             // chunk length  (NCH*PCH == LLEN)

// ---------------- Kernel 1: in_proj (1x1 conv, 96 -> 192) ----------------
// x: (B, 96, L) channel-major.  t0: (B, L, 192) row-major rows.
__global__ __launch_bounds__(256) void k_inproj(const float* __restrict__ x,
                                                const float* __restrict__ w,
                                                float* __restrict__ t0) {
    __shared__ float xin[CIN * 64];     // [c][l] stride 64
    __shared__ float wt[CIN * 65];      // [c][o] stride 65 (pad)
    int bid = blockIdx.x;
    int b = bid >> 8;                   // 256 l-tiles per batch
    int l0 = (bid & 255) << 6;
    int t = threadIdx.x;
    for (int i = 0; i < 24; ++i) {
        int idx = t + i * 256;          // 0..6143
        int c = idx >> 6, l = idx & 63;
        xin[c * 64 + l] = x[((size_t)(b * CIN + c)) * LLEN + l0 + l];
    }
    int o_lane = t & 63;
    int lgrp = t >> 6;                  // 0..3
    for (int ot = 0; ot < 3; ++ot) {
        __syncthreads();
        for (int i = 0; i < 24; ++i) {
            int idx = t + i * 256;      // 0..6143 over (o,c), c fastest
            int o = idx / 96, c = idx - o * 96;
            wt[c * 65 + o] = w[(ot * 64 + o) * 96 + c];
        }
        __syncthreads();
        float4 acc4[4];
        #pragma unroll
        for (int i = 0; i < 4; ++i) acc4[i] = make_float4(0.f, 0.f, 0.f, 0.f);
        int lb = lgrp * 16;
        for (int c = 0; c < CIN; ++c) {
            float wv = wt[c * 65 + o_lane];
            const float4* xv = reinterpret_cast<const float4*>(&xin[c * 64 + lb]);
            #pragma unroll
            for (int i = 0; i < 4; ++i) {
                float4 xx = xv[i];      // broadcast b128
                acc4[i].x += wv * xx.x; acc4[i].y += wv * xx.y;
                acc4[i].z += wv * xx.z; acc4[i].w += wv * xx.w;
            }
        }
        int o = ot * 64 + o_lane;
        #pragma unroll
        for (int i = 0; i < 4; ++i) {
            t0[((size_t)(b * LLEN) + l0 + lb + i * 4 + 0) * DI + o] = acc4[i].x;
            t0[((size_t)(b * LLEN) + l0 + lb + i * 4 + 1) * DI + o] = acc4[i].y;
            t0[((size_t)(b * LLEN) + l0 + lb + i * 4 + 2) * DI + o] = acc4[i].z;
            t0[((size_t)(b * LLEN) + l0 + lb + i * 4 + 3) * DI + o] = acc4[i].w;
        }
    }
}

// ------------- Kernel 2: depthwise 3x3 conv + bias + SiLU ---------------
__global__ __launch_bounds__(192) void k_dwconv(const float* __restrict__ t0,
                                                const float* __restrict__ cw,
                                                const float* __restrict__ cb,
                                                float* __restrict__ xf) {
    int bid = blockIdx.x;
    int wt = (bid & 15) << 3;           // 16 tiles of 8 along w
    int h  = (bid >> 4) & (HH - 1);
    int b  = bid >> 11;
    int d  = threadIdx.x;
    float acc[8];
    float bias = cb[d];
    #pragma unroll
    for (int j = 0; j < 8; ++j) acc[j] = bias;
    #pragma unroll
    for (int kh = 0; kh < 3; ++kh) {
        int hh = h + kh - 1;
        if (hh < 0 || hh >= HH) continue;
        float w0v = cw[d * 9 + kh * 3 + 0];
        float w1v = cw[d * 9 + kh * 3 + 1];
        float w2v = cw[d * 9 + kh * 3 + 2];
        const float* rowp = t0 + ((size_t)(b * LLEN) + hh * WWW) * DI + d;
        float v[10];
        #pragma unroll
        for (int j = 0; j < 10; ++j) {
            int ww = wt + j - 1;
            v[j] = (ww < 0 || ww >= WWW) ? 0.f : rowp[(size_t)ww * DI];
        }
        #pragma unroll
        for (int j = 0; j < 8; ++j)
            acc[j] += w0v * v[j] + w1v * v[j + 1] + w2v * v[j + 2];
    }
    size_t outbase = ((size_t)(b * LLEN) + h * WWW + wt) * DI + d;
    #pragma unroll
    for (int j = 0; j < 8; ++j) {
        float aa = acc[j];
        float s = aa * __builtin_amdgcn_rcpf(1.f + __expf(-aa));  // fast SiLU
        xf[outbase + (size_t)j * DI] = s;
    }
}

// ---- Kernel 3: phase-1 — fused gather + x_proj + chunk-summary scan ----
// Gathered rows stay on-chip: registers -> xs LDS ([d][p] stride 33,
// conflict-free for both the write and the scan-phase read).
__global__ __launch_bounds__(256) void k_scan1(const float* __restrict__ xf,
                                               const int* __restrict__ sids,
                                               const float* __restrict__ xpw,
                                               const float* __restrict__ dtw,
                                               const float* __restrict__ dtb,
                                               const float* __restrict__ alog,
                                               const float* __restrict__ dsv,
                                               float* __restrict__ cA,
                                               float* __restrict__ cB,
                                               float* __restrict__ xdblg) {
    __shared__ float xs[DI * 33];       // [d][p] stride 33
    __shared__ float part[32 * 4 * 9];  // [p][w][co] stride 9 (pad)
    __shared__ float xdbl[PCH * 8];     // [p][co]
    __shared__ int sid[PCH];
    int bid = blockIdx.x;
    int c = bid & (NCH - 1);
    int k = (bid >> 9) & 3;
    int b = bid >> 11;
    int t = threadIdx.x;
    if (t < PCH) sid[t] = sids[k * LLEN + c * PCH + t];
    __syncthreads();
    // fused gather + partial dots: thread (p, s): 24-float segment of row sid[p]
    {
        int p = t & 31, s = t >> 5;     // s in 0..7
        const float* row = xf + ((size_t)(b * LLEN) + sid[p]) * DI + s * 24;
        float4 v[6];
        #pragma unroll
        for (int j = 0; j < 6; ++j) v[j] = reinterpret_cast<const float4*>(row)[j];
        // stash the row segment into xs (u for the scan phase)
        #pragma unroll
        for (int j = 0; j < 6; ++j) {
            int d0 = s * 24 + j * 4;
            xs[(d0 + 0) * 33 + p] = v[j].x;
            xs[(d0 + 1) * 33 + p] = v[j].y;
            xs[(d0 + 2) * 33 + p] = v[j].z;
            xs[(d0 + 3) * 33 + p] = v[j].w;
        }
        const float* wbase = xpw + (size_t)k * 8 * DI + s * 24;
        float pd[8];
        #pragma unroll
        for (int co = 0; co < 8; ++co) {
            const float4* w4 = reinterpret_cast<const float4*>(wbase + co * DI);
            float a0 = 0.f;
            #pragma unroll
            for (int j = 0; j < 6; ++j) {
                float4 wv = w4[j];
                a0 += wv.x * v[j].x + wv.y * v[j].y + wv.z * v[j].z + wv.w * v[j].w;
            }
            pd[co] = a0;
        }
        // combine s with s^1 (lanes l and l^32 within the wave64)
        #pragma unroll
        for (int co = 0; co < 8; ++co) pd[co] += __shfl_xor(pd[co], 32);
        if ((s & 1) == 0) {
            int wq = s >> 1;            // 0..3
            #pragma unroll
            for (int co = 0; co < 8; ++co) part[(p * 4 + wq) * 9 + co] = pd[co];
        }
    }
    __syncthreads();
    // reduce 4 partials -> xdbl (LDS + global)
    {
        int p = t >> 3, co = t & 7;
        float s = part[(p * 4 + 0) * 9 + co] + part[(p * 4 + 1) * 9 + co] +
                  part[(p * 4 + 2) * 9 + co] + part[(p * 4 + 3) * 9 + co];
        xdbl[p * 8 + co] = s;
        xdblg[(size_t)bid * (PCH * 8) + t] = s;   // t == p*8+co
    }
    __syncthreads();
    if (t < DI) {
        int d = t;
        float wr[6];
        #pragma unroll
        for (int r = 0; r < 6; ++r) wr[r] = dtw[(k * DI + d) * 6 + r];
        float bias = dtb[k * DI + d];
        float A = -__expf(alog[k * DI + d]);
        float Ar = 1.f, Br = 0.f;
        const float4* xd4 = reinterpret_cast<const float4*>(xdbl);
        #pragma unroll
        for (int p = 0; p < PCH; ++p) {
            float4 x0 = xd4[p * 2], x1 = xd4[p * 2 + 1];   // broadcast b128
            float s = bias + wr[0] * x0.x + wr[1] * x0.y + wr[2] * x0.z +
                      wr[3] * x0.w + wr[4] * x1.x + wr[5] * x1.y;
            float delta = (s > 20.f) ? s : __logf(1.f + __expf(s));
            float a = __expf(delta * A);
            float bu = delta * x1.z * xs[d * 33 + p];      // u from LDS
            Br = a * Br + bu;
            Ar *= a;
        }
        cA[(size_t)bid * DI + d] = Ar;
        cB[(size_t)bid * DI + d] = Br;
    }
}

// ---- chunk-summary scans (3 tiny kernels; NSEG=16 segs of 32 chunks) ----
__global__ __launch_bounds__(192) void k_cs1(const float* __restrict__ cA,
                                             const float* __restrict__ cB,
                                             float* __restrict__ segA,
                                             float* __restrict__ segB) {
    int g = blockIdx.x;                 // bk*16 + seg
    int d = threadIdx.x;
    size_t base = (size_t)g * 32 * DI + d;
    float A = 1.f, Bv = 0.f;
    for (int cc = 0; cc < 32; ++cc) {
        float a = cA[base + (size_t)cc * DI];
        float bb = cB[base + (size_t)cc * DI];
        Bv = a * Bv + bb;
        A *= a;
    }
    segA[(size_t)g * DI + d] = A;
    segB[(size_t)g * DI + d] = Bv;
}
__global__ __launch_bounds__(192) void k_cs2(const float* __restrict__ segA,
                                             const float* __restrict__ segB,
                                             float* __restrict__ hseg) {
    int bk = blockIdx.x;                // 0..15
    int d = threadIdx.x;
    float h = 0.f;
    for (int seg = 0; seg < 16; ++seg) {
        size_t idx = (size_t)(bk * 16 + seg) * DI + d;
        hseg[idx] = h;
        h = segA[idx] * h + segB[idx];
    }
}
// writes per-chunk h0 INTO cB (aliased as hin), reading old cB first
__global__ __launch_bounds__(192) void k_cs3(const float* __restrict__ cA,
                                             float* __restrict__ cB,
                                             const float* __restrict__ hseg) {
    int g = blockIdx.x;                 // bk*16 + seg
    int d = threadIdx.x;
    float h = hseg[(size_t)g * DI + d];
    size_t base = (size_t)g * 32 * DI + d;
    for (int cc = 0; cc < 32; ++cc) {
        size_t ix = base + (size_t)cc * DI;
        float a = cA[ix];
        float bb = cB[ix];
        cB[ix] = h;                     // hin for this chunk
        h = a * h + bb;
    }
}

// ---- Kernel 5: phase-3 — scan replay + NON-ATOMIC scatter --------------
// One launch per direction k. Within a launch each (b,l,d) is written exactly
// once (scan_ids is a permutation), so plain RMW is race-free; launches are
// stream-ordered. ACCUM=false (k=0) initializes y, ACCUM=true adds.
template <bool ACCUM>
__global__ __launch_bounds__(192) void k_scan3(const float* __restrict__ xf,
                                               const int* __restrict__ sids,
                                               const float* __restrict__ dtw,
                                               const float* __restrict__ dtb,
                                               const float* __restrict__ alog,
                                               const float* __restrict__ dsv,
                                               const float* __restrict__ hin,
                                               const float* __restrict__ xdblg,
                                               float* __restrict__ y,
                                               int k) {
    __shared__ float xdbl[PCH * 8];
    __shared__ int sid[PCH];
    int bid = blockIdx.x;               // b*NCH + c
    int c = bid & (NCH - 1);
    int b = bid >> 9;
    int t = threadIdx.x;
    size_t gidx = (size_t)((b * KDIR + k) * NCH + c);
    if (t < PCH) sid[t] = sids[k * LLEN + c * PCH + t];
    if (t < 64) {
        reinterpret_cast<float4*>(xdbl)[t] =
            reinterpret_cast<const float4*>(xdblg + gidx * (PCH * 8))[t];
    }
    __syncthreads();
    int d = t;
    const float* ubase = xf + (size_t)(b * LLEN) * DI + d;
    float* ybase = y + (size_t)(b * LLEN) * DI + d;
    // batch-issue all gathered loads up front
    float uv[PCH];
    #pragma unroll
    for (int p = 0; p < PCH; ++p) uv[p] = ubase[(size_t)sid[p] * DI];
    float yv[PCH];
    if (ACCUM) {
        #pragma unroll
        for (int p = 0; p < PCH; ++p) yv[p] = ybase[(size_t)sid[p] * DI];
    }
    float wr[6];
    #pragma unroll
    for (int r = 0; r < 6; ++r) wr[r] = dtw[(k * DI + d) * 6 + r];
    float bias = dtb[k * DI + d];
    float A = -__expf(alog[k * DI + d]);
    float Dv = dsv[k * DI + d];
    float h = hin[gidx * DI + d];
    const float4* xd4 = reinterpret_cast<const float4*>(xdbl);
    #pragma unroll
    for (int p = 0; p < PCH; ++p) {
        float4 x0 = xd4[p * 2], x1 = xd4[p * 2 + 1];
        float s = bias + wr[0] * x0.x + wr[1] * x0.y + wr[2] * x0.z +
                  wr[3] * x0.w + wr[4] * x1.x + wr[5] * x1.y;
        float delta = (s > 20.f) ? s : __logf(1.f + __expf(s));
        float a = __expf(delta * A);
        float bu = delta * x1.z * uv[p];
        h = a * h + bu;
        float ys = x1.w * h + Dv * uv[p];
        if (ACCUM) ys += yv[p];
        ybase[(size_t)sid[p] * DI] = ys;    // plain store, no atomic
    }
}

// ------------- Kernel 6: GELU + out_proj (192 -> 96) --------------------
__global__ __launch_bounds__(256) void k_out(const float* __restrict__ y,
                                             const float* __restrict__ wo,
                                             float* __restrict__ out) {
    __shared__ float gy[DI * 65];       // [c][l] stride 65 (pad)
    int bid = blockIdx.x;
    int b = bid >> 8;
    int l0 = (bid & 255) << 6;
    int t = threadIdx.x;
    for (int i = 0; i < 48; ++i) {
        int idx = t + i * 256;          // 0..12287
        int l = idx / DI;
        int cc = idx - l * DI;
        float v = y[((size_t)(b * LLEN) + l0 + l) * DI + cc];
        float z = 0.7978845608028654f * (v + 0.044715f * v * v * v);
        float e = __expf(2.f * z);
        float th = 1.f - 2.f * __builtin_amdgcn_rcpf(e + 1.f);
        gy[cc * 65 + l] = 0.5f * v * (1.f + th);
    }
    __syncthreads();
    // thread = (lq, oh): 4 l's x 6 o's
    int lq = t & 15, oh = t >> 4;
    float acc[6][4];
    #pragma unroll
    for (int i = 0; i < 6; ++i)
        #pragma unroll
        for (int e = 0; e < 4; ++e) acc[i][e] = 0.f;
    for (int cc = 0; cc < DI; cc += 4) {
        float4 wv[6];
        #pragma unroll
        for (int i = 0; i < 6; ++i)
            wv[i] = *reinterpret_cast<const float4*>(&wo[(oh * 6 + i) * DI + cc]);
        float g[4][4];                  // [e_l][e_cc]
        #pragma unroll
        for (int el = 0; el < 4; ++el) {
            g[el][0] = gy[(cc + 0) * 65 + lq * 4 + el];
            g[el][1] = gy[(cc + 1) * 65 + lq * 4 + el];
            g[el][2] = gy[(cc + 2) * 65 + lq * 4 + el];
            g[el][3] = gy[(cc + 3) * 65 + lq * 4 + el];
        }
        #pragma unroll
        for (int i = 0; i < 6; ++i)
            #pragma unroll
            for (int el = 0; el < 4; ++el)
                acc[i][el] += wv[i].x * g[el][0] + wv[i].y * g[el][1] +
                              wv[i].z * g[el][2] + wv[i].w * g[el][3];
    }
    #pragma unroll
    for (int i = 0; i < 6; ++i) {
        int o = oh * 6 + i;
        float4 st = make_float4(acc[i][0], acc[i][1], acc[i][2], acc[i][3]);
        *reinterpret_cast<float4*>(&out[((size_t)(b * CIN) + o) * LLEN + l0 + lq * 4]) = st;
    }
}

extern "C" void kernel_launch(void* const* d_in, const int* in_sizes, int n_in,
                              void* d_out, int out_size, void* d_ws, size_t ws_size,
                              hipStream_t stream) {
    const float* x        = (const float*)d_in[0];
    const int*   scan_ids = (const int*)d_in[1];
    const float* in_proj_w = (const float*)d_in[3];
    const float* conv_w    = (const float*)d_in[4];
    const float* conv_b    = (const float*)d_in[5];
    const float* xpw       = (const float*)d_in[6];
    const float* dtw       = (const float*)d_in[7];
    const float* dtb       = (const float*)d_in[8];
    const float* alog      = (const float*)d_in[9];
    const float* dsv       = (const float*)d_in[10];
    const float* wo        = (const float*)d_in[11];
    float* out = (float*)d_out;

    float* ws = (float*)d_ws;
    const size_t NBL  = (size_t)BATCH * LLEN * DI;        // 12.58M floats
    const size_t NCK  = (size_t)BATCH * KDIR * NCH * DI;  // 1.57M floats
    const size_t NXD  = (size_t)BATCH * KDIR * LLEN * 8;  // 2.10M floats
    const size_t NSG  = (size_t)BATCH * KDIR * 16 * DI;   // 49152 floats
    float* t0    = ws;             // in_proj out; later reused as y
    float* xf    = t0 + NBL;
    float* xdblg = xf + NBL;
    float* cA    = xdblg + NXD;
    float* cB    = cA + NCK;       // becomes hin after k_cs3
    float* segA  = cB + NCK;
    float* segB  = segA + NSG;
    float* hseg  = segB + NSG;
    float* y     = t0;

    k_inproj<<<BATCH * 256, 256, 0, stream>>>(x, in_proj_w, t0);
    k_dwconv<<<BATCH * HH * 16, 192, 0, stream>>>(t0, conv_w, conv_b, xf);
    k_scan1<<<BATCH * KDIR * NCH, 256, 0, stream>>>(xf, scan_ids, xpw, dtw, dtb,
                                                    alog, dsv, cA, cB, xdblg);
    k_cs1<<<BATCH * KDIR * 16, 192, 0, stream>>>(cA, cB, segA, segB);
    k_cs2<<<BATCH * KDIR, 192, 0, stream>>>(segA, segB, hseg);
    k_cs3<<<BATCH * KDIR * 16, 192, 0, stream>>>(cA, cB, hseg);
    k_scan3<false><<<BATCH * NCH, 192, 0, stream>>>(xf, scan_ids, dtw, dtb,
                                                    alog, dsv, cB, xdblg, y, 0);
    for (int k = 1; k < KDIR; ++k)
        k_scan3<true><<<BATCH * NCH, 192, 0, stream>>>(xf, scan_ids, dtw, dtb,
                                                       alog, dsv, cB, xdblg, y, k);
    k_out<<<BATCH * 256, 256, 0, stream>>>(y, wo, out);
}

// Round 8
// 428.368 us; speedup vs baseline: 2.3753x; 1.0318x over previous
//
#include <hip/hip_runtime.h>
#include <math.h>

#define BATCH 4
#define HH 128
#define WWW 128
#define LLEN (HH*WWW)      // 16384
#define CIN 96
#define DI 192
#define KDIR 4
#define NCH 512            // number of chunks
#define PCH 32             // chunk length  (NCH*PCH == LLEN)

// ---------------- Kernel 1: in_proj (1x1 conv, 96 -> 192) ----------------
// x: (B, 96, L) channel-major.  t0: (B, L, 192) row-major rows.
__global__ __launch_bounds__(256) void k_inproj(const float* __restrict__ x,
                                                const float* __restrict__ w,
                                                float* __restrict__ t0) {
    __shared__ float xin[CIN * 64];     // [c][l] stride 64
    __shared__ float wt[CIN * 65];      // [c][o] stride 65 (pad)
    int bid = blockIdx.x;
    int b = bid >> 8;                   // 256 l-tiles per batch
    int l0 = (bid & 255) << 6;
    int t = threadIdx.x;
    for (int i = 0; i < 24; ++i) {
        int idx = t + i * 256;          // 0..6143
        int c = idx >> 6, l = idx & 63;
        xin[c * 64 + l] = x[((size_t)(b * CIN + c)) * LLEN + l0 + l];
    }
    int o_lane = t & 63;
    int lgrp = t >> 6;                  // 0..3
    for (int ot = 0; ot < 3; ++ot) {
        __syncthreads();
        for (int i = 0; i < 24; ++i) {
            int idx = t + i * 256;      // 0..6143 over (o,c), c fastest
            int o = idx / 96, c = idx - o * 96;
            wt[c * 65 + o] = w[(ot * 64 + o) * 96 + c];
        }
        __syncthreads();
        float4 acc4[4];
        #pragma unroll
        for (int i = 0; i < 4; ++i) acc4[i] = make_float4(0.f, 0.f, 0.f, 0.f);
        int lb = lgrp * 16;
        for (int c = 0; c < CIN; ++c) {
            float wv = wt[c * 65 + o_lane];
            const float4* xv = reinterpret_cast<const float4*>(&xin[c * 64 + lb]);
            #pragma unroll
            for (int i = 0; i < 4; ++i) {
                float4 xx = xv[i];      // broadcast b128
                acc4[i].x += wv * xx.x; acc4[i].y += wv * xx.y;
                acc4[i].z += wv * xx.z; acc4[i].w += wv * xx.w;
            }
        }
        int o = ot * 64 + o_lane;
        #pragma unroll
        for (int i = 0; i < 4; ++i) {
            t0[((size_t)(b * LLEN) + l0 + lb + i * 4 + 0) * DI + o] = acc4[i].x;
            t0[((size_t)(b * LLEN) + l0 + lb + i * 4 + 1) * DI + o] = acc4[i].y;
            t0[((size_t)(b * LLEN) + l0 + lb + i * 4 + 2) * DI + o] = acc4[i].z;
            t0[((size_t)(b * LLEN) + l0 + lb + i * 4 + 3) * DI + o] = acc4[i].w;
        }
    }
}

// ------------- Kernel 2: depthwise 3x3 conv + bias + SiLU ---------------
__global__ __launch_bounds__(192) void k_dwconv(const float* __restrict__ t0,
                                                const float* __restrict__ cw,
                                                const float* __restrict__ cb,
                                                float* __restrict__ xf) {
    int bid = blockIdx.x;
    int wt = (bid & 15) << 3;           // 16 tiles of 8 along w
    int h  = (bid >> 4) & (HH - 1);
    int b  = bid >> 11;
    int d  = threadIdx.x;
    float acc[8];
    float bias = cb[d];
    #pragma unroll
    for (int j = 0; j < 8; ++j) acc[j] = bias;
    #pragma unroll
    for (int kh = 0; kh < 3; ++kh) {
        int hh = h + kh - 1;
        if (hh < 0 || hh >= HH) continue;
        float w0v = cw[d * 9 + kh * 3 + 0];
        float w1v = cw[d * 9 + kh * 3 + 1];
        float w2v = cw[d * 9 + kh * 3 + 2];
        const float* rowp = t0 + ((size_t)(b * LLEN) + hh * WWW) * DI + d;
        float v[10];
        #pragma unroll
        for (int j = 0; j < 10; ++j) {
            int ww = wt + j - 1;
            v[j] = (ww < 0 || ww >= WWW) ? 0.f : rowp[(size_t)ww * DI];
        }
        #pragma unroll
        for (int j = 0; j < 8; ++j)
            acc[j] += w0v * v[j] + w1v * v[j + 1] + w2v * v[j + 2];
    }
    size_t outbase = ((size_t)(b * LLEN) + h * WWW + wt) * DI + d;
    #pragma unroll
    for (int j = 0; j < 8; ++j) {
        float aa = acc[j];
        float s = aa * __builtin_amdgcn_rcpf(1.f + __expf(-aa));  // fast SiLU
        xf[outbase + (size_t)j * DI] = s;
    }
}

// ---- Kernel 3: phase-1 — fused gather + x_proj + chunk-summary scan ----
// Weights staged in LDS (broadcast reads); gathered u kept on-chip as bf16.
__global__ __launch_bounds__(256) void k_scan1(const float* __restrict__ xf,
                                               const int* __restrict__ sids,
                                               const float* __restrict__ xpw,
                                               const float* __restrict__ dtw,
                                               const float* __restrict__ dtb,
                                               const float* __restrict__ alog,
                                               const float* __restrict__ dsv,
                                               float* __restrict__ cA,
                                               float* __restrict__ cB,
                                               float* __restrict__ xdblg) {
    __shared__ unsigned short xs[DI * 34];  // bf16 u, [d] stride 34, +p
    __shared__ float part[4 * 32 * 9];      // [wq][p][co]  (conflict-free writes)
    __shared__ float xdbl[PCH * 8];         // [p][co]
    __shared__ float wl[8 * DI];            // staged x_proj weights for this k
    int bid = blockIdx.x;
    int c = bid & (NCH - 1);
    int k = (bid >> 9) & 3;
    int b = bid >> 11;
    int t = threadIdx.x;
    int p = t & 31, s = t >> 5;             // s in 0..7: 24-float segment
    int myid = sids[k * LLEN + c * PCH + p];
    const float4* row = reinterpret_cast<const float4*>(
        xf + ((size_t)(b * LLEN) + myid) * DI + s * 24);
    float4 v[6];
    #pragma unroll
    for (int j = 0; j < 6; ++j) v[j] = row[j];
    // stage weights (1536 floats = 384 float4)
    {
        const float4* wsrc = reinterpret_cast<const float4*>(xpw + (size_t)k * 8 * DI);
        float4* wdst = reinterpret_cast<float4*>(wl);
        wdst[t] = wsrc[t];
        if (t < 128) wdst[256 + t] = wsrc[256 + t];
    }
    __syncthreads();
    // stash u as bf16 into xs
    #pragma unroll
    for (int j = 0; j < 6; ++j) {
        int d0 = s * 24 + j * 4;
        xs[(d0 + 0) * 34 + p] = (unsigned short)((__float_as_uint(v[j].x) + 0x8000u) >> 16);
        xs[(d0 + 1) * 34 + p] = (unsigned short)((__float_as_uint(v[j].y) + 0x8000u) >> 16);
        xs[(d0 + 2) * 34 + p] = (unsigned short)((__float_as_uint(v[j].z) + 0x8000u) >> 16);
        xs[(d0 + 3) * 34 + p] = (unsigned short)((__float_as_uint(v[j].w) + 0x8000u) >> 16);
    }
    // partial dots against LDS weights (broadcast reads)
    float pd[8];
    #pragma unroll
    for (int co = 0; co < 8; ++co) {
        const float4* w4 = reinterpret_cast<const float4*>(wl + co * DI + s * 24);
        float a0 = 0.f;
        #pragma unroll
        for (int j = 0; j < 6; ++j) {
            float4 wv = w4[j];
            a0 += wv.x * v[j].x + wv.y * v[j].y + wv.z * v[j].z + wv.w * v[j].w;
        }
        pd[co] = a0;
    }
    #pragma unroll
    for (int co = 0; co < 8; ++co) pd[co] += __shfl_xor(pd[co], 32);
    if ((s & 1) == 0) {
        int wq = s >> 1;                    // 0..3
        #pragma unroll
        for (int co = 0; co < 8; ++co) part[wq * 288 + p * 9 + co] = pd[co];
    }
    __syncthreads();
    // reduce 4 partials -> xdbl + xdblg
    {
        int p2 = t >> 3, co = t & 7;
        float sr = part[p2 * 9 + co] + part[288 + p2 * 9 + co] +
                   part[576 + p2 * 9 + co] + part[864 + p2 * 9 + co];
        xdbl[t] = sr;                       // t == p2*8+co
        xdblg[(size_t)bid * (PCH * 8) + t] = sr;
    }
    __syncthreads();
    if (t < DI) {
        int d = t;
        float wr[6];
        #pragma unroll
        for (int r = 0; r < 6; ++r) wr[r] = dtw[(k * DI + d) * 6 + r];
        float bias = dtb[k * DI + d];
        float A = -__expf(alog[k * DI + d]);
        float Ar = 1.f, Br = 0.f;
        const float4* xd4 = reinterpret_cast<const float4*>(xdbl);
        #pragma unroll
        for (int pp = 0; pp < PCH; ++pp) {
            float4 x0 = xd4[pp * 2], x1 = xd4[pp * 2 + 1];   // broadcast b128
            float sv = bias + wr[0] * x0.x + wr[1] * x0.y + wr[2] * x0.z +
                       wr[3] * x0.w + wr[4] * x1.x + wr[5] * x1.y;
            float delta = (sv > 20.f) ? sv : __logf(1.f + __expf(sv));
            float a = __expf(delta * A);
            float u = __uint_as_float((unsigned)xs[d * 34 + pp] << 16);
            float bu = delta * x1.z * u;
            Br = a * Br + bu;
            Ar *= a;
        }
        cA[(size_t)bid * DI + d] = Ar;
        cB[(size_t)bid * DI + d] = Br;
    }
}

// ---- chunk-summary scans (3 tiny kernels; NSEG=16 segs of 32 chunks) ----
__global__ __launch_bounds__(192) void k_cs1(const float* __restrict__ cA,
                                             const float* __restrict__ cB,
                                             float* __restrict__ segA,
                                             float* __restrict__ segB) {
    int g = blockIdx.x;                 // bk*16 + seg
    int d = threadIdx.x;
    size_t base = (size_t)g * 32 * DI + d;
    float A = 1.f, Bv = 0.f;
    for (int cc = 0; cc < 32; ++cc) {
        float a = cA[base + (size_t)cc * DI];
        float bb = cB[base + (size_t)cc * DI];
        Bv = a * Bv + bb;
        A *= a;
    }
    segA[(size_t)g * DI + d] = A;
    segB[(size_t)g * DI + d] = Bv;
}
__global__ __launch_bounds__(192) void k_cs2(const float* __restrict__ segA,
                                             const float* __restrict__ segB,
                                             float* __restrict__ hseg) {
    int bk = blockIdx.x;                // 0..15
    int d = threadIdx.x;
    float h = 0.f;
    for (int seg = 0; seg < 16; ++seg) {
        size_t idx = (size_t)(bk * 16 + seg) * DI + d;
        hseg[idx] = h;
        h = segA[idx] * h + segB[idx];
    }
}
// writes per-chunk h0 INTO cB (aliased as hin), reading old cB first
__global__ __launch_bounds__(192) void k_cs3(const float* __restrict__ cA,
                                             float* __restrict__ cB,
                                             const float* __restrict__ hseg) {
    int g = blockIdx.x;                 // bk*16 + seg
    int d = threadIdx.x;
    float h = hseg[(size_t)g * DI + d];
    size_t base = (size_t)g * 32 * DI + d;
    for (int cc = 0; cc < 32; ++cc) {
        size_t ix = base + (size_t)cc * DI;
        float a = cA[ix];
        float bb = cB[ix];
        cB[ix] = h;                     // hin for this chunk
        h = a * h + bb;
    }
}

// ---- Kernel 5: phase-3 — scan replay + NON-ATOMIC scatter --------------
// One launch per direction k. Within a launch each (b,l,d) is written exactly
// once (scan_ids is a permutation), so plain RMW is race-free; launches are
// stream-ordered. ACCUM=false (k=0) initializes y, ACCUM=true adds.
template <bool ACCUM>
__global__ __launch_bounds__(192) void k_scan3(const float* __restrict__ xf,
                                               const int* __restrict__ sids,
                                               const float* __restrict__ dtw,
                                               const float* __restrict__ dtb,
                                               const float* __restrict__ alog,
                                               const float* __restrict__ dsv,
                                               const float* __restrict__ hin,
                                               const float* __restrict__ xdblg,
                                               float* __restrict__ y,
                                               int k) {
    __shared__ float xdbl[PCH * 8];
    __shared__ int sid[PCH];
    int bid = blockIdx.x;               // b*NCH + c
    int c = bid & (NCH - 1);
    int b = bid >> 9;
    int t = threadIdx.x;
    size_t gidx = (size_t)((b * KDIR + k) * NCH + c);
    if (t < PCH) sid[t] = sids[k * LLEN + c * PCH + t];
    if (t < 64) {
        reinterpret_cast<float4*>(xdbl)[t] =
            reinterpret_cast<const float4*>(xdblg + gidx * (PCH * 8))[t];
    }
    __syncthreads();
    int d = t;
    const float* ubase = xf + (size_t)(b * LLEN) * DI + d;
    float* ybase = y + (size_t)(b * LLEN) * DI + d;
    // batch-issue all gathered loads up front
    float uv[PCH];
    #pragma unroll
    for (int p = 0; p < PCH; ++p) uv[p] = ubase[(size_t)sid[p] * DI];
    float yv[PCH];
    if (ACCUM) {
        #pragma unroll
        for (int p = 0; p < PCH; ++p) yv[p] = ybase[(size_t)sid[p] * DI];
    }
    float wr[6];
    #pragma unroll
    for (int r = 0; r < 6; ++r) wr[r] = dtw[(k * DI + d) * 6 + r];
    float bias = dtb[k * DI + d];
    float A = -__expf(alog[k * DI + d]);
    float Dv = dsv[k * DI + d];
    float h = hin[gidx * DI + d];
    const float4* xd4 = reinterpret_cast<const float4*>(xdbl);
    #pragma unroll
    for (int p = 0; p < PCH; ++p) {
        float4 x0 = xd4[p * 2], x1 = xd4[p * 2 + 1];
        float s = bias + wr[0] * x0.x + wr[1] * x0.y + wr[2] * x0.z +
                  wr[3] * x0.w + wr[4] * x1.x + wr[5] * x1.y;
        float delta = (s > 20.f) ? s : __logf(1.f + __expf(s));
        float a = __expf(delta * A);
        float bu = delta * x1.z * uv[p];
        h = a * h + bu;
        float ys = x1.w * h + Dv * uv[p];
        if (ACCUM) ys += yv[p];
        ybase[(size_t)sid[p] * DI] = ys;    // plain store, no atomic
    }
}

// ------------- Kernel 6: GELU + out_proj (192 -> 96) --------------------
__global__ __launch_bounds__(256) void k_out(const float* __restrict__ y,
                                             const float* __restrict__ wo,
                                             float* __restrict__ out) {
    __shared__ float gy[DI * 65];       // [c][l] stride 65 (pad)
    int bid = blockIdx.x;
    int b = bid >> 8;
    int l0 = (bid & 255) << 6;
    int t = threadIdx.x;
    for (int i = 0; i < 48; ++i) {
        int idx = t + i * 256;          // 0..12287
        int l = idx / DI;
        int cc = idx - l * DI;
        float v = y[((size_t)(b * LLEN) + l0 + l) * DI + cc];
        float z = 0.7978845608028654f * (v + 0.044715f * v * v * v);
        float e = __expf(2.f * z);
        float th = 1.f - 2.f * __builtin_amdgcn_rcpf(e + 1.f);
        gy[cc * 65 + l] = 0.5f * v * (1.f + th);
    }
    __syncthreads();
    // thread = (lq, oh): 4 l's x 6 o's
    int lq = t & 15, oh = t >> 4;
    float acc[6][4];
    #pragma unroll
    for (int i = 0; i < 6; ++i)
        #pragma unroll
        for (int e = 0; e < 4; ++e) acc[i][e] = 0.f;
    for (int cc = 0; cc < DI; cc += 4) {
        float4 wv[6];
        #pragma unroll
        for (int i = 0; i < 6; ++i)
            wv[i] = *reinterpret_cast<const float4*>(&wo[(oh * 6 + i) * DI + cc]);
        float g[4][4];                  // [e_l][e_cc]
        #pragma unroll
        for (int el = 0; el < 4; ++el) {
            g[el][0] = gy[(cc + 0) * 65 + lq * 4 + el];
            g[el][1] = gy[(cc + 1) * 65 + lq * 4 + el];
            g[el][2] = gy[(cc + 2) * 65 + lq * 4 + el];
            g[el][3] = gy[(cc + 3) * 65 + lq * 4 + el];
        }
        #pragma unroll
        for (int i = 0; i < 6; ++i)
            #pragma unroll
            for (int el = 0; el < 4; ++el)
                acc[i][el] += wv[i].x * g[el][0] + wv[i].y * g[el][1] +
                              wv[i].z * g[el][2] + wv[i].w * g[el][3];
    }
    #pragma unroll
    for (int i = 0; i < 6; ++i) {
        int o = oh * 6 + i;
        float4 st = make_float4(acc[i][0], acc[i][1], acc[i][2], acc[i][3]);
        *reinterpret_cast<float4*>(&out[((size_t)(b * CIN) + o) * LLEN + l0 + lq * 4]) = st;
    }
}

extern "C" void kernel_launch(void* const* d_in, const int* in_sizes, int n_in,
                              void* d_out, int out_size, void* d_ws, size_t ws_size,
                              hipStream_t stream) {
    const float* x        = (const float*)d_in[0];
    const int*   scan_ids = (const int*)d_in[1];
    const float* in_proj_w = (const float*)d_in[3];
    const float* conv_w    = (const float*)d_in[4];
    const float* conv_b    = (const float*)d_in[5];
    const float* xpw       = (const float*)d_in[6];
    const float* dtw       = (const float*)d_in[7];
    const float* dtb       = (const float*)d_in[8];
    const float* alog      = (const float*)d_in[9];
    const float* dsv       = (const float*)d_in[10];
    const float* wo        = (const float*)d_in[11];
    float* out = (float*)d_out;

    float* ws = (float*)d_ws;
    const size_t NBL  = (size_t)BATCH * LLEN * DI;        // 12.58M floats
    const size_t NCK  = (size_t)BATCH * KDIR * NCH * DI;  // 1.57M floats
    const size_t NXD  = (size_t)BATCH * KDIR * LLEN * 8;  // 2.10M floats
    const size_t NSG  = (size_t)BATCH * KDIR * 16 * DI;   // 49152 floats
    float* t0    = ws;             // in_proj out; later reused as y
    float* xf    = t0 + NBL;
    float* xdblg = xf + NBL;
    float* cA    = xdblg + NXD;
    float* cB    = cA + NCK;       // becomes hin after k_cs3
    float* segA  = cB + NCK;
    float* segB  = segA + NSG;
    float* hseg  = segB + NSG;
    float* y     = t0;

    k_inproj<<<BATCH * 256, 256, 0, stream>>>(x, in_proj_w, t0);
    k_dwconv<<<BATCH * HH * 16, 192, 0, stream>>>(t0, conv_w, conv_b, xf);
    k_scan1<<<BATCH * KDIR * NCH, 256, 0, stream>>>(xf, scan_ids, xpw, dtw, dtb,
                                                    alog, dsv, cA, cB, xdblg);
    k_cs1<<<BATCH * KDIR * 16, 192, 0, stream>>>(cA, cB, segA, segB);
    k_cs2<<<BATCH * KDIR, 192, 0, stream>>>(segA, segB, hseg);
    k_cs3<<<BATCH * KDIR * 16, 192, 0, stream>>>(cA, cB, hseg);
    k_scan3<false><<<BATCH * NCH, 192, 0, stream>>>(xf, scan_ids, dtw, dtb,
                                                    alog, dsv, cB, xdblg, y, 0);
    for (int k = 1; k < KDIR; ++k)
        k_scan3<true><<<BATCH * NCH, 192, 0, stream>>>(xf, scan_ids, dtw, dtb,
                                                       alog, dsv, cB, xdblg, y, k);
    k_out<<<BATCH * 256, 256, 0, stream>>>(y, wo, out);
}